// Round 9
// baseline (1923.688 us; speedup 1.0000x reference)
//
#include <hip/hip_runtime.h>
#include <hip/hip_fp16.h>

#define N_NODES 50000
#define N_EDGES 800000
#define NPAD 50176   // 196*256

typedef __attribute__((ext_vector_type(8))) short short8v;   // 8 bf16 (4 VGPR)
typedef __attribute__((ext_vector_type(4))) float f32x4;
typedef __attribute__((ext_vector_type(16))) float f32x16;
typedef __attribute__((ext_vector_type(2))) unsigned uint2v;

union U4S8 { uint4 u; short8v s; };
__device__ __forceinline__ short8v as_frag(uint4 u) { U4S8 t; t.u = u; return t.s; }
__device__ __forceinline__ uint4 zero4() { return make_uint4(0u, 0u, 0u, 0u); }

// direct global->LDS 16B copy (linear both sides)
__device__ __forceinline__ void gload_lds16(const uint4* g, uint4* l) {
    __builtin_amdgcn_global_load_lds((const __attribute__((address_space(1))) void*)g,
                                     (__attribute__((address_space(3))) void*)l, 16, 0, 0);
}

// ---------------- degree / CSR build ----------------

__global__ __launch_bounds__(256) void k_deg_i(const int* __restrict__ dst, int* __restrict__ degi) {
    int e = blockIdx.x * 256 + threadIdx.x;
    if (e < N_EDGES) atomicAdd(&degi[dst[e]], 1);
}

__global__ __launch_bounds__(256) void k_scan1(const int* __restrict__ degi, int* __restrict__ part,
                                               int* __restrict__ bsum, float* __restrict__ dinv) {
    __shared__ int tmp[256];
    int t = threadIdx.x, gid = blockIdx.x * 256 + t;
    int v = degi[gid];
    if (gid < N_NODES) dinv[gid] = rsqrtf((float)v + 1.0f);
    tmp[t] = v;
    __syncthreads();
    for (int off = 1; off < 256; off <<= 1) {
        int add = (t >= off) ? tmp[t - off] : 0;
        __syncthreads();
        tmp[t] += add;
        __syncthreads();
    }
    part[gid] = tmp[t] - v;
    if (t == 255) bsum[blockIdx.x] = tmp[t];
}

__global__ __launch_bounds__(256) void k_scan2(int* __restrict__ bsum) {
    __shared__ int tmp[256];
    int t = threadIdx.x;
    int v = (t < 196) ? bsum[t] : 0;
    tmp[t] = v;
    __syncthreads();
    for (int off = 1; off < 256; off <<= 1) {
        int add = (t >= off) ? tmp[t - off] : 0;
        __syncthreads();
        tmp[t] += add;
        __syncthreads();
    }
    if (t < 196) bsum[t] = tmp[t] - v;
}

__global__ __launch_bounds__(256) void k_scan3(const int* __restrict__ part, const int* __restrict__ bsum,
                                               int* __restrict__ rowp) {
    int gid = blockIdx.x * 256 + threadIdx.x;
    rowp[gid] = part[gid] + bsum[blockIdx.x];
}

__global__ __launch_bounds__(256) void k_place(const int* __restrict__ src, const int* __restrict__ dst,
                                               const float* __restrict__ dinv, const int* __restrict__ rowp,
                                               int* __restrict__ cur, int* __restrict__ es, float* __restrict__ en) {
    int e = blockIdx.x * 256 + threadIdx.x;
    if (e >= N_EDGES) return;
    int s = src[e], d = dst[e];
    int p = atomicAdd(&cur[d], 1);
    int slot = rowp[d] + p;
    es[slot] = s;
    en[slot] = dinv[s] * dinv[d];
}

// ---------------- weight / bias pre-pack (unchanged layouts) ----------------

__global__ __launch_bounds__(256) void k_wprep(const float* __restrict__ ew0, const float* __restrict__ ew,
                                               const float* __restrict__ ow0, const float* __restrict__ ow,
                                               const float* __restrict__ gw, unsigned* __restrict__ wpk) {
    int t = blockIdx.x * 256 + threadIdx.x;
    if (t >= 18 * 512) return;
    int lane = t & 63;
    int s = t >> 9;
    unsigned hu[8], lu[8];
    if (s < 14) {
        int q = (t >> 6) & 7;
        int mo = q >> 2, kts = q & 3;
        int fo = 32 * mo + (lane & 31);
#pragma unroll
        for (int i = 0; i < 8; ++i) {
            int fi = 16 * kts + 8 * (lane >> 5) + i;
            float w = 0.f;
            if (s == 0)       { if (fi < 16) w = ew0[fi * 64 + fo]; }
            else if (s <= 7)  w = ew[((s - 1) * 64 + fi) * 64 + fo];
            else if (s == 8)  w = ow0[(128 + fi) * 64 + fo];
            else if (s == 9)  w = ow0[fi * 64 + fo];
            else if (s == 10) w = ow0[(64 + fi) * 64 + fo];
            else              w = ow[((s - 11) * 64 + fi) * 64 + fo];
            unsigned u = __float_as_uint(w);
            unsigned h = u & 0xFFFF0000u;
            float d = w - __uint_as_float(h);
            hu[i] = h >> 16;
            lu[i] = __float_as_uint(d) >> 16;
        }
        uint4* o = (uint4*)wpk + (size_t)s * 1024 + (q * 2) * 64 + lane;
        o[0]  = make_uint4(hu[0] | (hu[1] << 16), hu[2] | (hu[3] << 16), hu[4] | (hu[5] << 16), hu[6] | (hu[7] << 16));
        o[64] = make_uint4(lu[0] | (lu[1] << 16), lu[2] | (lu[3] << 16), lu[4] | (lu[5] << 16), lu[6] | (lu[7] << 16));
    } else {
        int nt = (t >> 6) & 3;
        int kt = (t >> 8) & 1;
        int n = nt * 16 + (lane & 15);
#pragma unroll
        for (int i = 0; i < 8; ++i) {
            int k = kt * 32 + ((lane >> 4) * 8) + i;
            float w = gw[((s - 14) * 64 + k) * 64 + n];
            unsigned u = __float_as_uint(w);
            unsigned h = u & 0xFFFF0000u;
            float d = w - __uint_as_float(h);
            hu[i] = h >> 16;
            lu[i] = __float_as_uint(d) >> 16;
        }
        uint4* o = (uint4*)(wpk + (size_t)t * 8);
        o[0] = make_uint4(hu[0] | (hu[1] << 16), hu[2] | (hu[3] << 16), hu[4] | (hu[5] << 16), hu[6] | (hu[7] << 16));
        o[1] = make_uint4(lu[0] | (lu[1] << 16), lu[2] | (lu[3] << 16), lu[4] | (lu[5] << 16), lu[6] | (lu[7] << 16));
    }
}

__global__ __launch_bounds__(256) void k_bprep(const float* __restrict__ eb0, const float* __restrict__ eb,
                                               const float* __restrict__ ob0, const float* __restrict__ ob,
                                               const float* __restrict__ finw, const float* __restrict__ finb,
                                               float* __restrict__ bias3) {
    int t = blockIdx.x * 256 + threadIdx.x;
    if (t >= 1024) return;
    if (t == 15 * 64) { bias3[t] = finb[0]; return; }
    if (t > 15 * 64)  { bias3[t] = 0.f; return; }
    int s = t >> 6, idx = t & 63;
    int j = idx & 3, l5 = (idx >> 2) & 1, q = (idx >> 3) & 3, mo = idx >> 5;
    int f = 32 * mo + 8 * q + 4 * l5 + j;
    float b = 0.f;
    if (s == 0) b = eb0[f];
    else if (s <= 7) b = eb[(s - 1) * 64 + f];
    else if (s == 8) b = ob0[f];
    else if (s >= 11 && s <= 13) b = ob[(s - 11) * 64 + f];
    else if (s == 14) b = finw[f];
    bias3[t] = b;
}

// ---------------- shared split helpers ----------------

__device__ __forceinline__ void split_pack8(const float* xv, uint4& hfrag, uint4& lfrag) {
    unsigned hu[8], lu[8];
#pragma unroll
    for (int i = 0; i < 8; ++i) {
        unsigned u = __float_as_uint(xv[i]);
        unsigned h = u & 0xFFFF0000u;
        float d = xv[i] - __uint_as_float(h);
        hu[i] = h >> 16;
        lu[i] = __float_as_uint(d) >> 16;
    }
    hfrag = make_uint4(hu[0] | (hu[1] << 16), hu[2] | (hu[3] << 16), hu[4] | (hu[5] << 16), hu[6] | (hu[7] << 16));
    lfrag = make_uint4(lu[0] | (lu[1] << 16), lu[2] | (lu[3] << 16), lu[4] | (lu[5] << 16), lu[6] | (lu[7] << 16));
}

__device__ __forceinline__ void load_a_global_kt(const float* rowp, int kt, int g, uint4& aH, uint4& aL) {
    const float4* r4 = (const float4*)(rowp + kt * 32 + g * 8);
    float4 f0 = r4[0], f1 = r4[1];
    float xv[8] = {f0.x, f0.y, f0.z, f0.w, f1.x, f1.y, f1.z, f1.w};
    split_pack8(xv, aH, aL);
}

// 16x16x32 B-operand mfma (gcn node GEMM only)
__device__ __forceinline__ void mfma_stage(f32x4 acc[2][4], const uint4* wqs,
                                           const uint4 aH[2][2], const uint4 aL[2][2], int lane) {
#pragma unroll
    for (int kt = 0; kt < 2; ++kt) {
#pragma unroll
        for (int nt = 0; nt < 4; ++nt) {
            const uint4* wq = wqs + ((size_t)((kt * 4 + nt) * 64 + lane)) * 2;
            short8v bh = as_frag(wq[0]);
            short8v bl = as_frag(wq[1]);
#pragma unroll
            for (int mt = 0; mt < 2; ++mt) {
                short8v ah = as_frag(aH[mt][kt]);
                short8v al = as_frag(aL[mt][kt]);
                acc[mt][nt] = __builtin_amdgcn_mfma_f32_16x16x32_bf16(ah, bh, acc[mt][nt], 0, 0, 0);
                acc[mt][nt] = __builtin_amdgcn_mfma_f32_16x16x32_bf16(al, bh, acc[mt][nt], 0, 0, 0);
                acc[mt][nt] = __builtin_amdgcn_mfma_f32_16x16x32_bf16(ah, bl, acc[mt][nt], 0, 0, 0);
            }
        }
    }
}

// ---------------- GCN node GEMM: writes xl as f16 ----------------

__global__ __launch_bounds__(256, 3) void k_xlm(const float* __restrict__ xin,
                                                const unsigned* __restrict__ wpk, int stage,
                                                __half* __restrict__ xlh) {
    const int tid = threadIdx.x;
    const int wv = tid >> 6, lane = tid & 63;
    const int g = lane >> 4, l15 = lane & 15;
    const int rb = blockIdx.x * 128 + wv * 32;
    const uint4* wq = (const uint4*)wpk + (size_t)stage * 1024;

    f32x4 acc[2][4];
    uint4 aH[2][2], aL[2][2];
#pragma unroll
    for (int mt = 0; mt < 2; ++mt) {
        int row = rb + mt * 16 + l15;
        if (row < N_NODES) {
            const float* rowp = xin + (size_t)row * 64;
#pragma unroll
            for (int kt = 0; kt < 2; ++kt) load_a_global_kt(rowp, kt, g, aH[mt][kt], aL[mt][kt]);
        } else {
#pragma unroll
            for (int kt = 0; kt < 2; ++kt) { aH[mt][kt] = zero4(); aL[mt][kt] = zero4(); }
        }
#pragma unroll
        for (int nt = 0; nt < 4; ++nt) acc[mt][nt] = (f32x4){0.f, 0.f, 0.f, 0.f};
    }
    mfma_stage(acc, wq, aH, aL, lane);
#pragma unroll
    for (int mt = 0; mt < 2; ++mt)
#pragma unroll
        for (int nt = 0; nt < 4; ++nt)
#pragma unroll
            for (int r = 0; r < 4; ++r) {
                int row = rb + mt * 16 + g * 4 + r;
                if (row < N_NODES) xlh[(size_t)row * 64 + nt * 16 + l15] = __float2half(acc[mt][nt][r]);
            }
}

// ---------------- segmented aggregation: f16 gathers, shfl-broadcast es/en ----------------

__global__ __launch_bounds__(256) void k_agg(const __half* __restrict__ xlh,
                                             const int* __restrict__ es, const float* __restrict__ en,
                                             const int* __restrict__ rowp, const float* __restrict__ dinv,
                                             const float* __restrict__ b, float* __restrict__ xout,
                                             unsigned short* __restrict__ oh, unsigned short* __restrict__ ol,
                                             int writeSplit) {
    int n = blockIdx.x * 4 + (threadIdx.x >> 6);
    int j = threadIdx.x & 63;
    if (n >= N_NODES) return;
    const int i0 = rowp[n], e1 = rowp[n + 1];
    float a0 = 0.f, a1 = 0.f, a2 = 0.f, a3 = 0.f;
    for (int base = i0; base < e1; base += 64) {
        int cnt = e1 - base;
        if (cnt > 64) cnt = 64;
        int se = 0;
        float we = 0.f;
        if (base + j < e1) { se = es[base + j]; we = en[base + j]; }
        int k = 0;
        for (; k + 4 <= cnt; k += 4) {
            int s0 = __shfl(se, k + 0); float w0 = __shfl(we, k + 0);
            int s1 = __shfl(se, k + 1); float w1 = __shfl(we, k + 1);
            int s2 = __shfl(se, k + 2); float w2 = __shfl(we, k + 2);
            int s3 = __shfl(se, k + 3); float w3 = __shfl(we, k + 3);
            a0 = fmaf(w0, __half2float(xlh[(size_t)s0 * 64 + j]), a0);
            a1 = fmaf(w1, __half2float(xlh[(size_t)s1 * 64 + j]), a1);
            a2 = fmaf(w2, __half2float(xlh[(size_t)s2 * 64 + j]), a2);
            a3 = fmaf(w3, __half2float(xlh[(size_t)s3 * 64 + j]), a3);
        }
        for (; k < cnt; ++k) {
            int s0 = __shfl(se, k); float w0 = __shfl(we, k);
            a0 = fmaf(w0, __half2float(xlh[(size_t)s0 * 64 + j]), a0);
        }
    }
    float di = dinv[n];
    float val = (a0 + a1) + (a2 + a3) + di * di * __half2float(xlh[(size_t)n * 64 + j]) + b[j];
    float v = fmaxf(val, 0.f);
    size_t idx = (size_t)n * 64 + j;
    xout[idx] = v;
    if (writeSplit) {
        unsigned u = __float_as_uint(v);
        oh[idx] = (unsigned short)(u >> 16);
        float d = v - __uint_as_float(u & 0xFFFF0000u);
        ol[idx] = (unsigned short)(__float_as_uint(d) >> 16);
    }
}

// ---------------- fused edge mega kernel v6: 2 B-tiles per wave ----------------
// wave = 64 edges (two 32-edge tiles); block = 256 edges; A-frag ds_reads shared
// across both tiles (1 ds_read : 3 MFMA); barriers/staging per edge halved.

__device__ __forceinline__ void bias_init32(f32x16 acc[2], const float* bp) {
#pragma unroll
    for (int mo = 0; mo < 2; ++mo)
#pragma unroll
        for (int q = 0; q < 4; ++q) {
            float4 b = *(const float4*)(bp + (mo * 4 + q) * 8);
            acc[mo][4 * q + 0] = b.x;
            acc[mo][4 * q + 1] = b.y;
            acc[mo][4 * q + 2] = b.z;
            acc[mo][4 * q + 3] = b.w;
        }
}

// relu + split + native transpose via permlane32_swap.
__device__ __forceinline__ void exchange32(const f32x16 acc[2], unsigned BH[4][4], unsigned BL[4][4]) {
#pragma unroll
    for (int kts = 0; kts < 4; ++kts) {
        const int mo = kts >> 1;
        const int base = 8 * (kts & 1);
        float r0 = fmaxf(acc[mo][base + 0], 0.f), r1 = fmaxf(acc[mo][base + 1], 0.f);
        float r2 = fmaxf(acc[mo][base + 2], 0.f), r3 = fmaxf(acc[mo][base + 3], 0.f);
        float r4 = fmaxf(acc[mo][base + 4], 0.f), r5 = fmaxf(acc[mo][base + 5], 0.f);
        float r6 = fmaxf(acc[mo][base + 6], 0.f), r7 = fmaxf(acc[mo][base + 7], 0.f);
        unsigned pA0, pA1, pB0, pB1;
        asm("v_cvt_pk_bf16_f32 %0, %1, %2" : "=v"(pA0) : "v"(r0), "v"(r1));
        asm("v_cvt_pk_bf16_f32 %0, %1, %2" : "=v"(pA1) : "v"(r2), "v"(r3));
        asm("v_cvt_pk_bf16_f32 %0, %1, %2" : "=v"(pB0) : "v"(r4), "v"(r5));
        asm("v_cvt_pk_bf16_f32 %0, %1, %2" : "=v"(pB1) : "v"(r6), "v"(r7));
        float d0 = r0 - __uint_as_float(pA0 << 16);
        float d1 = r1 - __uint_as_float(pA0 & 0xFFFF0000u);
        float d2 = r2 - __uint_as_float(pA1 << 16);
        float d3 = r3 - __uint_as_float(pA1 & 0xFFFF0000u);
        float d4 = r4 - __uint_as_float(pB0 << 16);
        float d5 = r5 - __uint_as_float(pB0 & 0xFFFF0000u);
        float d6 = r6 - __uint_as_float(pB1 << 16);
        float d7 = r7 - __uint_as_float(pB1 & 0xFFFF0000u);
        unsigned qA0, qA1, qB0, qB1;
        asm("v_cvt_pk_bf16_f32 %0, %1, %2" : "=v"(qA0) : "v"(d0), "v"(d1));
        asm("v_cvt_pk_bf16_f32 %0, %1, %2" : "=v"(qA1) : "v"(d2), "v"(d3));
        asm("v_cvt_pk_bf16_f32 %0, %1, %2" : "=v"(qB0) : "v"(d4), "v"(d5));
        asm("v_cvt_pk_bf16_f32 %0, %1, %2" : "=v"(qB1) : "v"(d6), "v"(d7));
        uint2v sw0 = __builtin_amdgcn_permlane32_swap(pA0, pB0, false, false);
        uint2v sw1 = __builtin_amdgcn_permlane32_swap(pA1, pB1, false, false);
        BH[kts][0] = sw0[0]; BH[kts][1] = sw1[0]; BH[kts][2] = sw0[1]; BH[kts][3] = sw1[1];
        uint2v tw0 = __builtin_amdgcn_permlane32_swap(qA0, qB0, false, false);
        uint2v tw1 = __builtin_amdgcn_permlane32_swap(qA1, qB1, false, false);
        BL[kts][0] = tw0[0]; BL[kts][1] = tw1[0]; BL[kts][2] = tw0[1]; BL[kts][3] = tw1[1];
    }
}

__device__ __forceinline__ void loadB32(const unsigned short* xhi, const unsigned short* xlo,
                                        int node, int l5, unsigned BH[4][4], unsigned BL[4][4]) {
    const uint4* hp = (const uint4*)xhi + (size_t)node * 8;
    const uint4* lp = (const uint4*)xlo + (size_t)node * 8;
#pragma unroll
    for (int kts = 0; kts < 4; ++kts) {
        uint4 h = hp[2 * kts + l5];
        BH[kts][0] = h.x; BH[kts][1] = h.y; BH[kts][2] = h.z; BH[kts][3] = h.w;
        uint4 l = lp[2 * kts + l5];
        BL[kts][0] = l.x; BL[kts][1] = l.y; BL[kts][2] = l.z; BL[kts][3] = l.w;
    }
}

// shared-A dual-tile MFMA: 2 ds_reads serve 6 MFMAs
template <int KTS>
__device__ __forceinline__ void mfma32x2(f32x16 acc0[2], f32x16 acc1[2], const uint4* wl,
                                         const unsigned BH0[4][4], const unsigned BL0[4][4],
                                         const unsigned BH1[4][4], const unsigned BL1[4][4], int lane) {
#pragma unroll
    for (int kt = 0; kt < KTS; ++kt) {
        short8v Bh0 = as_frag(make_uint4(BH0[kt][0], BH0[kt][1], BH0[kt][2], BH0[kt][3]));
        short8v Bl0 = as_frag(make_uint4(BL0[kt][0], BL0[kt][1], BL0[kt][2], BL0[kt][3]));
        short8v Bh1 = as_frag(make_uint4(BH1[kt][0], BH1[kt][1], BH1[kt][2], BH1[kt][3]));
        short8v Bl1 = as_frag(make_uint4(BL1[kt][0], BL1[kt][1], BL1[kt][2], BL1[kt][3]));
#pragma unroll
        for (int mo = 0; mo < 2; ++mo) {
            short8v Ah = as_frag(wl[((mo * 4 + kt) * 2 + 0) * 64 + lane]);
            short8v Al = as_frag(wl[((mo * 4 + kt) * 2 + 1) * 64 + lane]);
            acc0[mo] = __builtin_amdgcn_mfma_f32_32x32x16_bf16(Ah, Bh0, acc0[mo], 0, 0, 0);
            acc1[mo] = __builtin_amdgcn_mfma_f32_32x32x16_bf16(Ah, Bh1, acc1[mo], 0, 0, 0);
            acc0[mo] = __builtin_amdgcn_mfma_f32_32x32x16_bf16(Al, Bh0, acc0[mo], 0, 0, 0);
            acc1[mo] = __builtin_amdgcn_mfma_f32_32x32x16_bf16(Al, Bh1, acc1[mo], 0, 0, 0);
            acc0[mo] = __builtin_amdgcn_mfma_f32_32x32x16_bf16(Ah, Bl0, acc0[mo], 0, 0, 0);
            acc1[mo] = __builtin_amdgcn_mfma_f32_32x32x16_bf16(Ah, Bl1, acc1[mo], 0, 0, 0);
        }
    }
}

__device__ __forceinline__ void loadEA(const float* ea, int e, int l5, unsigned BH[4][4], unsigned BL[4][4]) {
    const float4* ar = (const float4*)(ea + (size_t)e * 16 + 8 * l5);
    float4 f0 = ar[0], f1 = ar[1];
    float xv[8] = {f0.x, f0.y, f0.z, f0.w, f1.x, f1.y, f1.z, f1.w};
    uint4 hf, lf;
    split_pack8(xv, hf, lf);
    BH[0][0] = hf.x; BH[0][1] = hf.y; BH[0][2] = hf.z; BH[0][3] = hf.w;
    BL[0][0] = lf.x; BL[0][1] = lf.y; BL[0][2] = lf.z; BL[0][3] = lf.w;
}

__global__ __launch_bounds__(256, 3) void k_mega(
    const float* __restrict__ ea, const int* __restrict__ src, const int* __restrict__ dst,
    const unsigned short* __restrict__ xhi, const unsigned short* __restrict__ xlo,
    const unsigned* __restrict__ wpk, const float* __restrict__ bias3,
    float* __restrict__ out) {
    __shared__ uint4 wlds[2][1024];   // 2 x 16 KB weight double-buffer
    __shared__ float blds[1024];      // bias / fin_w table
    const int tid = threadIdx.x;
    const int wv = tid >> 6, lane = tid & 63;
    const int l5 = lane >> 5, n = lane & 31;
    const int e0 = blockIdx.x * 256 + wv * 64 + n;   // tile0 edge
    const int e1 = e0 + 32;                          // tile1 edge
    const uint4* wpk4 = (const uint4*)wpk;

    // prologue: stage-0 weights (direct to LDS) + bias table
#pragma unroll
    for (int j = 0; j < 4; ++j) gload_lds16(wpk4 + tid + 256 * j, &wlds[0][tid + 256 * j]);
#pragma unroll
    for (int j = 0; j < 4; ++j) blds[tid + 256 * j] = bias3[tid + 256 * j];

    const int nsrc0 = src[e0], nsrc1 = src[e1];
    const int ndst0 = dst[e0], ndst1 = dst[e1];

    f32x16 acc0[2], acc1[2];
    unsigned BH0[4][4], BL0[4][4], BH1[4][4], BL1[4][4];

    // s0 B-frags from edge_attr (K=16, slice 0 only)
    loadEA(ea, e0, l5, BH0, BL0);
    loadEA(ea, e1, l5, BH1, BL1);
    __syncthreads();

    for (int s = 0; s < 14; ++s) {
        if (s < 13) {   // async direct-to-LDS prefetch of next-stage weights
            const uint4* np = wpk4 + (size_t)(s + 1) * 1024;
            uint4* nb = wlds[(s + 1) & 1];
#pragma unroll
            for (int j = 0; j < 4; ++j) gload_lds16(np + tid + 256 * j, &nb[tid + 256 * j]);
        }
        const uint4* wl = wlds[s & 1];
        if (s == 0) {
            bias_init32(acc0, blds + l5 * 4);
            bias_init32(acc1, blds + l5 * 4);
            mfma32x2<1>(acc0, acc1, wl, BH0, BL0, BH1, BL1, lane);
        } else if (s == 9 || s == 10) {
            loadB32(xhi, xlo, (s == 9) ? nsrc0 : ndst0, l5, BH0, BL0);
            loadB32(xhi, xlo, (s == 9) ? nsrc1 : ndst1, l5, BH1, BL1);
            mfma32x2<4>(acc0, acc1, wl, BH0, BL0, BH1, BL1, lane);   // accumulate
        } else {
            exchange32(acc0, BH0, BL0);
            bias_init32(acc0, blds + s * 64 + l5 * 4);
            exchange32(acc1, BH1, BL1);
            bias_init32(acc1, blds + s * 64 + l5 * 4);
            mfma32x2<4>(acc0, acc1, wl, BH0, BL0, BH1, BL1, lane);
        }
        __syncthreads();
    }

    // final dot: out = relu(P14)^T . fin_w + fin_b  (both tiles)
    float v0 = 0.f, v1 = 0.f;
#pragma unroll
    for (int mo = 0; mo < 2; ++mo)
#pragma unroll
        for (int q = 0; q < 4; ++q) {
            float4 w4 = *(const float4*)(blds + 14 * 64 + (mo * 4 + q) * 8 + l5 * 4);
            v0 = fmaf(fmaxf(acc0[mo][4 * q + 0], 0.f), w4.x, v0);
            v0 = fmaf(fmaxf(acc0[mo][4 * q + 1], 0.f), w4.y, v0);
            v0 = fmaf(fmaxf(acc0[mo][4 * q + 2], 0.f), w4.z, v0);
            v0 = fmaf(fmaxf(acc0[mo][4 * q + 3], 0.f), w4.w, v0);
            v1 = fmaf(fmaxf(acc1[mo][4 * q + 0], 0.f), w4.x, v1);
            v1 = fmaf(fmaxf(acc1[mo][4 * q + 1], 0.f), w4.y, v1);
            v1 = fmaf(fmaxf(acc1[mo][4 * q + 2], 0.f), w4.z, v1);
            v1 = fmaf(fmaxf(acc1[mo][4 * q + 3], 0.f), w4.w, v1);
        }
    v0 += __shfl_xor(v0, 32, 64);
    v1 += __shfl_xor(v1, 32, 64);
    if (lane < 32) {
        float fb = blds[15 * 64];
        out[e0] = v0 + fb;
        out[e1] = v1 + fb;
    }
}

// ---------------- launch ----------------

extern "C" void kernel_launch(void* const* d_in, const int* in_sizes, int n_in,
                              void* d_out, int out_size, void* d_ws, size_t ws_size,
                              hipStream_t stream) {
    (void)in_sizes; (void)n_in; (void)out_size; (void)ws_size;

    const float* x         = (const float*)d_in[0];
    const int*   src       = (const int*)d_in[1];
    const int*   dst       = (const int*)d_in[2];
    const float* edge_attr = (const float*)d_in[3];
    const float* gcn_w     = (const float*)d_in[4];
    const float* gcn_b     = (const float*)d_in[5];
    const float* edge_w0   = (const float*)d_in[6];
    const float* edge_b0   = (const float*)d_in[7];
    const float* edge_w    = (const float*)d_in[8];
    const float* edge_b    = (const float*)d_in[9];
    const float* out_w0    = (const float*)d_in[10];
    const float* out_b0    = (const float*)d_in[11];
    const float* out_w     = (const float*)d_in[12];
    const float* out_b     = (const float*)d_in[13];
    const float* fin_w     = (const float*)d_in[14];
    const float* fin_b     = (const float*)d_in[15];
    float* out = (float*)d_out;

    float* ws    = (float*)d_ws;
    float* dinv  = ws;                                  // NPAD
    float* xbufA = dinv + NPAD;                         // N*64 f32
    __half* xlh  = (__half*)(xbufA + N_NODES * 64);     // N*64 f16
    unsigned short* xhi = (unsigned short*)((float*)xlh + N_NODES * 64);  // N*64 u16
    unsigned short* xlo = xhi + N_NODES * 64;                             // N*64 u16
    float* scr   = (float*)(xlo + N_NODES * 64);
    unsigned* wpk   = (unsigned*)scr;                   // 18*4096 = 73728 u32
    float* bias3    = scr + 73728;                      // 1024 padded
    int* degi       = (int*)(scr + 74816);              // NPAD
    int* cur        = degi + NPAD;                      // NPAD (adjacent for one memset)
    int* part       = cur + NPAD;                       // NPAD
    int* bsum       = part + NPAD;                      // 256
    int* rowp       = bsum + 256;                       // NPAD
    int* es         = rowp + NPAD;                      // E
    float* en       = (float*)(es + N_EDGES);           // E

    const int EB = N_EDGES / 256;                       // 3125
    const int NB = NPAD / 256;                          // 196

    hipMemsetAsync(degi, 0, 2 * NPAD * sizeof(int), stream);
    k_deg_i<<<EB, 256, 0, stream>>>(dst, degi);
    k_scan1<<<NB, 256, 0, stream>>>(degi, part, bsum, dinv);
    k_scan2<<<1, 256, 0, stream>>>(bsum);
    k_scan3<<<NB, 256, 0, stream>>>(part, bsum, rowp);
    k_place<<<EB, 256, 0, stream>>>(src, dst, dinv, rowp, cur, es, en);

    k_wprep<<<36, 256, 0, stream>>>(edge_w0, edge_w, out_w0, out_w, gcn_w, wpk);
    k_bprep<<<4, 256, 0, stream>>>(edge_b0, edge_b, out_b0, out_b, fin_w, fin_b, bias3);

    const float* xin = x;
    for (int layer = 0; layer < 4; ++layer) {
        k_xlm<<<(NPAD / 128), 256, 0, stream>>>(xin, wpk, 14 + layer, xlh);
        k_agg<<<(N_NODES + 3) / 4, 256, 0, stream>>>(xlh, es, en, rowp, dinv,
                                                     gcn_b + layer * 64, xbufA,
                                                     xhi, xlo, (layer == 3) ? 1 : 0);
        xin = xbufA;
    }

    k_mega<<<N_EDGES / 256, 256, 0, stream>>>(edge_attr, src, dst, xhi, xlo,
                                              wpk, bias3, out);
}

// Round 10
// 1193.490 us; speedup vs baseline: 1.6118x; 1.6118x over previous
//
#include <hip/hip_runtime.h>
#include <hip/hip_fp16.h>

#define N_NODES 50000
#define N_EDGES 800000
#define NPAD 50176   // 196*256

typedef __attribute__((ext_vector_type(8))) short short8v;   // 8 bf16 (4 VGPR)
typedef __attribute__((ext_vector_type(4))) float f32x4;
typedef __attribute__((ext_vector_type(16))) float f32x16;
typedef __attribute__((ext_vector_type(2))) unsigned uint2v;

union U4S8 { uint4 u; short8v s; };
__device__ __forceinline__ short8v as_frag(uint4 u) { U4S8 t; t.u = u; return t.s; }
__device__ __forceinline__ uint4 zero4() { return make_uint4(0u, 0u, 0u, 0u); }

// direct global->LDS 16B copy (linear both sides)
__device__ __forceinline__ void gload_lds16(const uint4* g, uint4* l) {
    __builtin_amdgcn_global_load_lds((const __attribute__((address_space(1))) void*)g,
                                     (__attribute__((address_space(3))) void*)l, 16, 0, 0);
}

// ---------------- degree / CSR build ----------------

__global__ __launch_bounds__(256) void k_deg_i(const int* __restrict__ dst, int* __restrict__ degi) {
    int e = blockIdx.x * 256 + threadIdx.x;
    if (e < N_EDGES) atomicAdd(&degi[dst[e]], 1);
}

__global__ __launch_bounds__(256) void k_scan1(const int* __restrict__ degi, int* __restrict__ part,
                                               int* __restrict__ bsum, float* __restrict__ dinv) {
    __shared__ int tmp[256];
    int t = threadIdx.x, gid = blockIdx.x * 256 + t;
    int v = degi[gid];
    if (gid < N_NODES) dinv[gid] = rsqrtf((float)v + 1.0f);
    tmp[t] = v;
    __syncthreads();
    for (int off = 1; off < 256; off <<= 1) {
        int add = (t >= off) ? tmp[t - off] : 0;
        __syncthreads();
        tmp[t] += add;
        __syncthreads();
    }
    part[gid] = tmp[t] - v;
    if (t == 255) bsum[blockIdx.x] = tmp[t];
}

__global__ __launch_bounds__(256) void k_scan2(int* __restrict__ bsum) {
    __shared__ int tmp[256];
    int t = threadIdx.x;
    int v = (t < 196) ? bsum[t] : 0;
    tmp[t] = v;
    __syncthreads();
    for (int off = 1; off < 256; off <<= 1) {
        int add = (t >= off) ? tmp[t - off] : 0;
        __syncthreads();
        tmp[t] += add;
        __syncthreads();
    }
    if (t < 196) bsum[t] = tmp[t] - v;
}

__global__ __launch_bounds__(256) void k_scan3(const int* __restrict__ part, const int* __restrict__ bsum,
                                               int* __restrict__ rowp) {
    int gid = blockIdx.x * 256 + threadIdx.x;
    rowp[gid] = part[gid] + bsum[blockIdx.x];
}

__global__ __launch_bounds__(256) void k_place(const int* __restrict__ src, const int* __restrict__ dst,
                                               const float* __restrict__ dinv, const int* __restrict__ rowp,
                                               int* __restrict__ cur, int* __restrict__ es, float* __restrict__ en) {
    int e = blockIdx.x * 256 + threadIdx.x;
    if (e >= N_EDGES) return;
    int s = src[e], d = dst[e];
    int p = atomicAdd(&cur[d], 1);
    int slot = rowp[d] + p;
    es[slot] = s;
    en[slot] = dinv[s] * dinv[d];
}

// ---------------- weight / bias pre-pack (unchanged layouts) ----------------

__global__ __launch_bounds__(256) void k_wprep(const float* __restrict__ ew0, const float* __restrict__ ew,
                                               const float* __restrict__ ow0, const float* __restrict__ ow,
                                               const float* __restrict__ gw, unsigned* __restrict__ wpk) {
    int t = blockIdx.x * 256 + threadIdx.x;
    if (t >= 18 * 512) return;
    int lane = t & 63;
    int s = t >> 9;
    unsigned hu[8], lu[8];
    if (s < 14) {
        int q = (t >> 6) & 7;
        int mo = q >> 2, kts = q & 3;
        int fo = 32 * mo + (lane & 31);
#pragma unroll
        for (int i = 0; i < 8; ++i) {
            int fi = 16 * kts + 8 * (lane >> 5) + i;
            float w = 0.f;
            if (s == 0)       { if (fi < 16) w = ew0[fi * 64 + fo]; }
            else if (s <= 7)  w = ew[((s - 1) * 64 + fi) * 64 + fo];
            else if (s == 8)  w = ow0[(128 + fi) * 64 + fo];
            else if (s == 9)  w = ow0[fi * 64 + fo];
            else if (s == 10) w = ow0[(64 + fi) * 64 + fo];
            else              w = ow[((s - 11) * 64 + fi) * 64 + fo];
            unsigned u = __float_as_uint(w);
            unsigned h = u & 0xFFFF0000u;
            float d = w - __uint_as_float(h);
            hu[i] = h >> 16;
            lu[i] = __float_as_uint(d) >> 16;
        }
        uint4* o = (uint4*)wpk + (size_t)s * 1024 + (q * 2) * 64 + lane;
        o[0]  = make_uint4(hu[0] | (hu[1] << 16), hu[2] | (hu[3] << 16), hu[4] | (hu[5] << 16), hu[6] | (hu[7] << 16));
        o[64] = make_uint4(lu[0] | (lu[1] << 16), lu[2] | (lu[3] << 16), lu[4] | (lu[5] << 16), lu[6] | (lu[7] << 16));
    } else {
        int nt = (t >> 6) & 3;
        int kt = (t >> 8) & 1;
        int n = nt * 16 + (lane & 15);
#pragma unroll
        for (int i = 0; i < 8; ++i) {
            int k = kt * 32 + ((lane >> 4) * 8) + i;
            float w = gw[((s - 14) * 64 + k) * 64 + n];
            unsigned u = __float_as_uint(w);
            unsigned h = u & 0xFFFF0000u;
            float d = w - __uint_as_float(h);
            hu[i] = h >> 16;
            lu[i] = __float_as_uint(d) >> 16;
        }
        uint4* o = (uint4*)(wpk + (size_t)t * 8);
        o[0] = make_uint4(hu[0] | (hu[1] << 16), hu[2] | (hu[3] << 16), hu[4] | (hu[5] << 16), hu[6] | (hu[7] << 16));
        o[1] = make_uint4(lu[0] | (lu[1] << 16), lu[2] | (lu[3] << 16), lu[4] | (lu[5] << 16), lu[6] | (lu[7] << 16));
    }
}

__global__ __launch_bounds__(256) void k_bprep(const float* __restrict__ eb0, const float* __restrict__ eb,
                                               const float* __restrict__ ob0, const float* __restrict__ ob,
                                               const float* __restrict__ finw, const float* __restrict__ finb,
                                               float* __restrict__ bias3) {
    int t = blockIdx.x * 256 + threadIdx.x;
    if (t >= 1024) return;
    if (t == 15 * 64) { bias3[t] = finb[0]; return; }
    if (t > 15 * 64)  { bias3[t] = 0.f; return; }
    int s = t >> 6, idx = t & 63;
    int j = idx & 3, l5 = (idx >> 2) & 1, q = (idx >> 3) & 3, mo = idx >> 5;
    int f = 32 * mo + 8 * q + 4 * l5 + j;
    float b = 0.f;
    if (s == 0) b = eb0[f];
    else if (s <= 7) b = eb[(s - 1) * 64 + f];
    else if (s == 8) b = ob0[f];
    else if (s >= 11 && s <= 13) b = ob[(s - 11) * 64 + f];
    else if (s == 14) b = finw[f];
    bias3[t] = b;
}

// ---------------- shared split helpers ----------------

__device__ __forceinline__ void split_pack8(const float* xv, uint4& hfrag, uint4& lfrag) {
    unsigned hu[8], lu[8];
#pragma unroll
    for (int i = 0; i < 8; ++i) {
        unsigned u = __float_as_uint(xv[i]);
        unsigned h = u & 0xFFFF0000u;
        float d = xv[i] - __uint_as_float(h);
        hu[i] = h >> 16;
        lu[i] = __float_as_uint(d) >> 16;
    }
    hfrag = make_uint4(hu[0] | (hu[1] << 16), hu[2] | (hu[3] << 16), hu[4] | (hu[5] << 16), hu[6] | (hu[7] << 16));
    lfrag = make_uint4(lu[0] | (lu[1] << 16), lu[2] | (lu[3] << 16), lu[4] | (lu[5] << 16), lu[6] | (lu[7] << 16));
}

__device__ __forceinline__ void load_a_global_kt(const float* rowp, int kt, int g, uint4& aH, uint4& aL) {
    const float4* r4 = (const float4*)(rowp + kt * 32 + g * 8);
    float4 f0 = r4[0], f1 = r4[1];
    float xv[8] = {f0.x, f0.y, f0.z, f0.w, f1.x, f1.y, f1.z, f1.w};
    split_pack8(xv, aH, aL);
}

// 16x16x32 B-operand mfma (gcn node GEMM only)
__device__ __forceinline__ void mfma_stage(f32x4 acc[2][4], const uint4* wqs,
                                           const uint4 aH[2][2], const uint4 aL[2][2], int lane) {
#pragma unroll
    for (int kt = 0; kt < 2; ++kt) {
#pragma unroll
        for (int nt = 0; nt < 4; ++nt) {
            const uint4* wq = wqs + ((size_t)((kt * 4 + nt) * 64 + lane)) * 2;
            short8v bh = as_frag(wq[0]);
            short8v bl = as_frag(wq[1]);
#pragma unroll
            for (int mt = 0; mt < 2; ++mt) {
                short8v ah = as_frag(aH[mt][kt]);
                short8v al = as_frag(aL[mt][kt]);
                acc[mt][nt] = __builtin_amdgcn_mfma_f32_16x16x32_bf16(ah, bh, acc[mt][nt], 0, 0, 0);
                acc[mt][nt] = __builtin_amdgcn_mfma_f32_16x16x32_bf16(al, bh, acc[mt][nt], 0, 0, 0);
                acc[mt][nt] = __builtin_amdgcn_mfma_f32_16x16x32_bf16(ah, bl, acc[mt][nt], 0, 0, 0);
            }
        }
    }
}

// ---------------- GCN node GEMM: writes xl as f16 ----------------

__global__ __launch_bounds__(256, 3) void k_xlm(const float* __restrict__ xin,
                                                const unsigned* __restrict__ wpk, int stage,
                                                __half* __restrict__ xlh) {
    const int tid = threadIdx.x;
    const int wv = tid >> 6, lane = tid & 63;
    const int g = lane >> 4, l15 = lane & 15;
    const int rb = blockIdx.x * 128 + wv * 32;
    const uint4* wq = (const uint4*)wpk + (size_t)stage * 1024;

    f32x4 acc[2][4];
    uint4 aH[2][2], aL[2][2];
#pragma unroll
    for (int mt = 0; mt < 2; ++mt) {
        int row = rb + mt * 16 + l15;
        if (row < N_NODES) {
            const float* rowp = xin + (size_t)row * 64;
#pragma unroll
            for (int kt = 0; kt < 2; ++kt) load_a_global_kt(rowp, kt, g, aH[mt][kt], aL[mt][kt]);
        } else {
#pragma unroll
            for (int kt = 0; kt < 2; ++kt) { aH[mt][kt] = zero4(); aL[mt][kt] = zero4(); }
        }
#pragma unroll
        for (int nt = 0; nt < 4; ++nt) acc[mt][nt] = (f32x4){0.f, 0.f, 0.f, 0.f};
    }
    mfma_stage(acc, wq, aH, aL, lane);
#pragma unroll
    for (int mt = 0; mt < 2; ++mt)
#pragma unroll
        for (int nt = 0; nt < 4; ++nt)
#pragma unroll
            for (int r = 0; r < 4; ++r) {
                int row = rb + mt * 16 + g * 4 + r;
                if (row < N_NODES) xlh[(size_t)row * 64 + nt * 16 + l15] = __float2half(acc[mt][nt][r]);
            }
}

// ---------------- segmented aggregation: f16 gathers, shfl-broadcast es/en ----------------

__global__ __launch_bounds__(256) void k_agg(const __half* __restrict__ xlh,
                                             const int* __restrict__ es, const float* __restrict__ en,
                                             const int* __restrict__ rowp, const float* __restrict__ dinv,
                                             const float* __restrict__ b, float* __restrict__ xout,
                                             unsigned short* __restrict__ oh, unsigned short* __restrict__ ol,
                                             int writeSplit) {
    int n = blockIdx.x * 4 + (threadIdx.x >> 6);
    int j = threadIdx.x & 63;
    if (n >= N_NODES) return;
    const int i0 = rowp[n], e1 = rowp[n + 1];
    float a0 = 0.f, a1 = 0.f, a2 = 0.f, a3 = 0.f;
    for (int base = i0; base < e1; base += 64) {
        int cnt = e1 - base;
        if (cnt > 64) cnt = 64;
        int se = 0;
        float we = 0.f;
        if (base + j < e1) { se = es[base + j]; we = en[base + j]; }
        int k = 0;
        for (; k + 4 <= cnt; k += 4) {
            int s0 = __shfl(se, k + 0); float w0 = __shfl(we, k + 0);
            int s1 = __shfl(se, k + 1); float w1 = __shfl(we, k + 1);
            int s2 = __shfl(se, k + 2); float w2 = __shfl(we, k + 2);
            int s3 = __shfl(se, k + 3); float w3 = __shfl(we, k + 3);
            a0 = fmaf(w0, __half2float(xlh[(size_t)s0 * 64 + j]), a0);
            a1 = fmaf(w1, __half2float(xlh[(size_t)s1 * 64 + j]), a1);
            a2 = fmaf(w2, __half2float(xlh[(size_t)s2 * 64 + j]), a2);
            a3 = fmaf(w3, __half2float(xlh[(size_t)s3 * 64 + j]), a3);
        }
        for (; k < cnt; ++k) {
            int s0 = __shfl(se, k); float w0 = __shfl(we, k);
            a0 = fmaf(w0, __half2float(xlh[(size_t)s0 * 64 + j]), a0);
        }
    }
    float di = dinv[n];
    float val = (a0 + a1) + (a2 + a3) + di * di * __half2float(xlh[(size_t)n * 64 + j]) + b[j];
    float v = fmaxf(val, 0.f);
    size_t idx = (size_t)n * 64 + j;
    xout[idx] = v;
    if (writeSplit) {
        unsigned u = __float_as_uint(v);
        oh[idx] = (unsigned short)(u >> 16);
        float d = v - __uint_as_float(u & 0xFFFF0000u);
        ol[idx] = (unsigned short)(__float_as_uint(d) >> 16);
    }
}

// ---------------- fused edge mega kernel v7: half-stage (8KB) staging, 8 blocks/CU ----------------
// Single 32-edge tile per wave (R8 registers). Each stage split into two mo-halves:
// half-stage hs = 2s+mo stages 8KB (mo's weight fragments), computes acc[mo]'s 12 MFMAs.
// LDS = 2x8KB + 4KB bias = 20KB -> 8 blocks/CU; cross-block wave mix de-phases exchange/MFMA.

__device__ __forceinline__ void bias_init_mo(f32x16& a, const float* bp, int mo) {
#pragma unroll
    for (int q = 0; q < 4; ++q) {
        float4 b = *(const float4*)(bp + (mo * 4 + q) * 8);
        a[4 * q + 0] = b.x;
        a[4 * q + 1] = b.y;
        a[4 * q + 2] = b.z;
        a[4 * q + 3] = b.w;
    }
}

// relu + split + native transpose via permlane32_swap.
__device__ __forceinline__ void exchange32(const f32x16 acc[2], unsigned BH[4][4], unsigned BL[4][4]) {
#pragma unroll
    for (int kts = 0; kts < 4; ++kts) {
        const int mo = kts >> 1;
        const int base = 8 * (kts & 1);
        float r0 = fmaxf(acc[mo][base + 0], 0.f), r1 = fmaxf(acc[mo][base + 1], 0.f);
        float r2 = fmaxf(acc[mo][base + 2], 0.f), r3 = fmaxf(acc[mo][base + 3], 0.f);
        float r4 = fmaxf(acc[mo][base + 4], 0.f), r5 = fmaxf(acc[mo][base + 5], 0.f);
        float r6 = fmaxf(acc[mo][base + 6], 0.f), r7 = fmaxf(acc[mo][base + 7], 0.f);
        unsigned pA0, pA1, pB0, pB1;
        asm("v_cvt_pk_bf16_f32 %0, %1, %2" : "=v"(pA0) : "v"(r0), "v"(r1));
        asm("v_cvt_pk_bf16_f32 %0, %1, %2" : "=v"(pA1) : "v"(r2), "v"(r3));
        asm("v_cvt_pk_bf16_f32 %0, %1, %2" : "=v"(pB0) : "v"(r4), "v"(r5));
        asm("v_cvt_pk_bf16_f32 %0, %1, %2" : "=v"(pB1) : "v"(r6), "v"(r7));
        float d0 = r0 - __uint_as_float(pA0 << 16);
        float d1 = r1 - __uint_as_float(pA0 & 0xFFFF0000u);
        float d2 = r2 - __uint_as_float(pA1 << 16);
        float d3 = r3 - __uint_as_float(pA1 & 0xFFFF0000u);
        float d4 = r4 - __uint_as_float(pB0 << 16);
        float d5 = r5 - __uint_as_float(pB0 & 0xFFFF0000u);
        float d6 = r6 - __uint_as_float(pB1 << 16);
        float d7 = r7 - __uint_as_float(pB1 & 0xFFFF0000u);
        unsigned qA0, qA1, qB0, qB1;
        asm("v_cvt_pk_bf16_f32 %0, %1, %2" : "=v"(qA0) : "v"(d0), "v"(d1));
        asm("v_cvt_pk_bf16_f32 %0, %1, %2" : "=v"(qA1) : "v"(d2), "v"(d3));
        asm("v_cvt_pk_bf16_f32 %0, %1, %2" : "=v"(qB0) : "v"(d4), "v"(d5));
        asm("v_cvt_pk_bf16_f32 %0, %1, %2" : "=v"(qB1) : "v"(d6), "v"(d7));
        uint2v sw0 = __builtin_amdgcn_permlane32_swap(pA0, pB0, false, false);
        uint2v sw1 = __builtin_amdgcn_permlane32_swap(pA1, pB1, false, false);
        BH[kts][0] = sw0[0]; BH[kts][1] = sw1[0]; BH[kts][2] = sw0[1]; BH[kts][3] = sw1[1];
        uint2v tw0 = __builtin_amdgcn_permlane32_swap(qA0, qB0, false, false);
        uint2v tw1 = __builtin_amdgcn_permlane32_swap(qA1, qB1, false, false);
        BL[kts][0] = tw0[0]; BL[kts][1] = tw1[0]; BL[kts][2] = tw0[1]; BL[kts][3] = tw1[1];
    }
}

__device__ __forceinline__ void loadB32(const unsigned short* xhi, const unsigned short* xlo,
                                        int node, int l5, unsigned BH[4][4], unsigned BL[4][4]) {
    const uint4* hp = (const uint4*)xhi + (size_t)node * 8;
    const uint4* lp = (const uint4*)xlo + (size_t)node * 8;
#pragma unroll
    for (int kts = 0; kts < 4; ++kts) {
        uint4 h = hp[2 * kts + l5];
        BH[kts][0] = h.x; BH[kts][1] = h.y; BH[kts][2] = h.z; BH[kts][3] = h.w;
        uint4 l = lp[2 * kts + l5];
        BL[kts][0] = l.x; BL[kts][1] = l.y; BL[kts][2] = l.z; BL[kts][3] = l.w;
    }
}

__device__ __forceinline__ void loadEA(const float* ea, int e, int l5, unsigned BH[4][4], unsigned BL[4][4]) {
    const float4* ar = (const float4*)(ea + (size_t)e * 16 + 8 * l5);
    float4 f0 = ar[0], f1 = ar[1];
    float xv[8] = {f0.x, f0.y, f0.z, f0.w, f1.x, f1.y, f1.z, f1.w};
    uint4 hf, lf;
    split_pack8(xv, hf, lf);
    BH[0][0] = hf.x; BH[0][1] = hf.y; BH[0][2] = hf.z; BH[0][3] = hf.w;
    BL[0][0] = lf.x; BL[0][1] = lf.y; BL[0][2] = lf.z; BL[0][3] = lf.w;
}

// 12 MFMAs of one mo-half from an 8KB half buffer (local layout: [kt][h][lane])
template <int KTS>
__device__ __forceinline__ void mfma_half(f32x16& a, const uint4* wl,
                                          const unsigned BH[4][4], const unsigned BL[4][4], int lane) {
#pragma unroll
    for (int kt = 0; kt < KTS; ++kt) {
        short8v Bh = as_frag(make_uint4(BH[kt][0], BH[kt][1], BH[kt][2], BH[kt][3]));
        short8v Bl = as_frag(make_uint4(BL[kt][0], BL[kt][1], BL[kt][2], BL[kt][3]));
        short8v Ah = as_frag(wl[(kt * 2 + 0) * 64 + lane]);
        short8v Al = as_frag(wl[(kt * 2 + 1) * 64 + lane]);
        a = __builtin_amdgcn_mfma_f32_32x32x16_bf16(Ah, Bh, a, 0, 0, 0);
        a = __builtin_amdgcn_mfma_f32_32x32x16_bf16(Al, Bh, a, 0, 0, 0);
        a = __builtin_amdgcn_mfma_f32_32x32x16_bf16(Ah, Bl, a, 0, 0, 0);
    }
}

__global__ __launch_bounds__(256, 6) void k_mega(
    const float* __restrict__ ea, const int* __restrict__ src, const int* __restrict__ dst,
    const unsigned short* __restrict__ xhi, const unsigned short* __restrict__ xlo,
    const unsigned* __restrict__ wpk, const float* __restrict__ bias3,
    float* __restrict__ out) {
    __shared__ uint4 wlds[2][512];    // 2 x 8 KB rolling half-stage weight buffers
    __shared__ float blds[1024];      // bias / fin_w table (4 KB)
    const int tid = threadIdx.x;
    const int wv = tid >> 6, lane = tid & 63;
    const int l5 = lane >> 5, n = lane & 31;
    const int e = blockIdx.x * 128 + wv * 32 + n;
    const uint4* wpk4 = (const uint4*)wpk;

    // prologue: half-stage 0 (s0, mo0) weights direct-to-LDS + bias table
    gload_lds16(wpk4 + tid, &wlds[0][tid]);
    gload_lds16(wpk4 + tid + 256, &wlds[0][tid + 256]);
#pragma unroll
    for (int j = 0; j < 4; ++j) blds[tid + 256 * j] = bias3[tid + 256 * j];

    const int nsrc = src[e];
    const int ndst = dst[e];

    f32x16 acc[2];
    unsigned BH[4][4], BL[4][4];

    // s0 B-frags from edge_attr (K=16, slice 0 only)
    loadEA(ea, e, l5, BH, BL);
    __syncthreads();

    for (int hs = 0; hs < 28; ++hs) {
        const int s = hs >> 1, mo = hs & 1;
        if (hs < 27) {   // async direct-to-LDS prefetch of next half-stage
            const int h1 = hs + 1;
            const uint4* np = wpk4 + (size_t)(h1 >> 1) * 1024 + (size_t)(h1 & 1) * 512;
            uint4* nb = wlds[h1 & 1];
            gload_lds16(np + tid, &nb[tid]);
            gload_lds16(np + tid + 256, &nb[tid + 256]);
        }
        const uint4* wl = wlds[hs & 1];
        if (mo == 0) {    // stage entry: produce B-frags for this stage
            if (s == 9 || s == 10) loadB32(xhi, xlo, (s == 9) ? nsrc : ndst, l5, BH, BL);
            else if (s != 0)       exchange32(acc, BH, BL);
        }
        if (s != 9 && s != 10) bias_init_mo(acc[mo], blds + s * 64, mo);
        if (s == 0) mfma_half<1>(acc[mo], wl, BH, BL, lane);
        else        mfma_half<4>(acc[mo], wl, BH, BL, lane);
        __syncthreads();
    }

    // final dot: out = relu(P14)^T . fin_w + fin_b
    float v = 0.f;
#pragma unroll
    for (int mo = 0; mo < 2; ++mo)
#pragma unroll
        for (int q = 0; q < 4; ++q) {
            float4 w4 = *(const float4*)(blds + 14 * 64 + (mo * 4 + q) * 8 + l5 * 4);
            v = fmaf(fmaxf(acc[mo][4 * q + 0], 0.f), w4.x, v);
            v = fmaf(fmaxf(acc[mo][4 * q + 1], 0.f), w4.y, v);
            v = fmaf(fmaxf(acc[mo][4 * q + 2], 0.f), w4.z, v);
            v = fmaf(fmaxf(acc[mo][4 * q + 3], 0.f), w4.w, v);
        }
    v += __shfl_xor(v, 32, 64);
    if (lane < 32) out[e] = v + blds[15 * 64];
}

// ---------------- launch ----------------

extern "C" void kernel_launch(void* const* d_in, const int* in_sizes, int n_in,
                              void* d_out, int out_size, void* d_ws, size_t ws_size,
                              hipStream_t stream) {
    (void)in_sizes; (void)n_in; (void)out_size; (void)ws_size;

    const float* x         = (const float*)d_in[0];
    const int*   src       = (const int*)d_in[1];
    const int*   dst       = (const int*)d_in[2];
    const float* edge_attr = (const float*)d_in[3];
    const float* gcn_w     = (const float*)d_in[4];
    const float* gcn_b     = (const float*)d_in[5];
    const float* edge_w0   = (const float*)d_in[6];
    const float* edge_b0   = (const float*)d_in[7];
    const float* edge_w    = (const float*)d_in[8];
    const float* edge_b    = (const float*)d_in[9];
    const float* out_w0    = (const float*)d_in[10];
    const float* out_b0    = (const float*)d_in[11];
    const float* out_w     = (const float*)d_in[12];
    const float* out_b     = (const float*)d_in[13];
    const float* fin_w     = (const float*)d_in[14];
    const float* fin_b     = (const float*)d_in[15];
    float* out = (float*)d_out;

    float* ws    = (float*)d_ws;
    float* dinv  = ws;                                  // NPAD
    float* xbufA = dinv + NPAD;                         // N*64 f32
    __half* xlh  = (__half*)(xbufA + N_NODES * 64);     // N*64 f16
    unsigned short* xhi = (unsigned short*)((float*)xlh + N_NODES * 64);  // N*64 u16
    unsigned short* xlo = xhi + N_NODES * 64;                             // N*64 u16
    float* scr   = (float*)(xlo + N_NODES * 64);
    unsigned* wpk   = (unsigned*)scr;                   // 18*4096 = 73728 u32
    float* bias3    = scr + 73728;                      // 1024 padded
    int* degi       = (int*)(scr + 74816);              // NPAD
    int* cur        = degi + NPAD;                      // NPAD (adjacent for one memset)
    int* part       = cur + NPAD;                       // NPAD
    int* bsum       = part + NPAD;                      // 256
    int* rowp       = bsum + 256;                       // NPAD
    int* es         = rowp + NPAD;                      // E
    float* en       = (float*)(es + N_EDGES);           // E

    const int EB = N_EDGES / 256;                       // 3125
    const int NB = NPAD / 256;                          // 196

    hipMemsetAsync(degi, 0, 2 * NPAD * sizeof(int), stream);
    k_deg_i<<<EB, 256, 0, stream>>>(dst, degi);
    k_scan1<<<NB, 256, 0, stream>>>(degi, part, bsum, dinv);
    k_scan2<<<1, 256, 0, stream>>>(bsum);
    k_scan3<<<NB, 256, 0, stream>>>(part, bsum, rowp);
    k_place<<<EB, 256, 0, stream>>>(src, dst, dinv, rowp, cur, es, en);

    k_wprep<<<36, 256, 0, stream>>>(edge_w0, edge_w, out_w0, out_w, gcn_w, wpk);
    k_bprep<<<4, 256, 0, stream>>>(edge_b0, edge_b, out_b0, out_b, fin_w, fin_b, bias3);

    const float* xin = x;
    for (int layer = 0; layer < 4; ++layer) {
        k_xlm<<<(NPAD / 128), 256, 0, stream>>>(xin, wpk, 14 + layer, xlh);
        k_agg<<<(N_NODES + 3) / 4, 256, 0, stream>>>(xlh, es, en, rowp, dinv,
                                                     gcn_b + layer * 64, xbufA,
                                                     xhi, xlo, (layer == 3) ? 1 : 0);
        xin = xbufA;
    }

    k_mega<<<N_EDGES / 128, 256, 0, stream>>>(edge_attr, src, dst, xhi, xlo,
                                              wpk, bias3, out);
}

// Round 11
// 500.675 us; speedup vs baseline: 3.8422x; 2.3838x over previous
//
#include <hip/hip_runtime.h>
#include <hip/hip_fp16.h>

#define N_NODES 50000
#define N_EDGES 800000
#define NPAD 50176   // 196*256

typedef __attribute__((ext_vector_type(8))) short short8v;   // 8 bf16 (4 VGPR)
typedef __attribute__((ext_vector_type(4))) float f32x4;
typedef __attribute__((ext_vector_type(16))) float f32x16;
typedef __attribute__((ext_vector_type(2))) unsigned uint2v;

union U4S8 { uint4 u; short8v s; };
__device__ __forceinline__ short8v as_frag(uint4 u) { U4S8 t; t.u = u; return t.s; }
__device__ __forceinline__ uint4 zero4() { return make_uint4(0u, 0u, 0u, 0u); }

// direct global->LDS 16B copy (linear both sides)
__device__ __forceinline__ void gload_lds16(const uint4* g, uint4* l) {
    __builtin_amdgcn_global_load_lds((const __attribute__((address_space(1))) void*)g,
                                     (__attribute__((address_space(3))) void*)l, 16, 0, 0);
}

// ---------------- degree / CSR build ----------------

__global__ __launch_bounds__(256) void k_deg_i(const int* __restrict__ dst, int* __restrict__ degi) {
    int e = blockIdx.x * 256 + threadIdx.x;
    if (e < N_EDGES) atomicAdd(&degi[dst[e]], 1);
}

__global__ __launch_bounds__(256) void k_scan1(const int* __restrict__ degi, int* __restrict__ part,
                                               int* __restrict__ bsum, float* __restrict__ dinv) {
    __shared__ int tmp[256];
    int t = threadIdx.x, gid = blockIdx.x * 256 + t;
    int v = degi[gid];
    if (gid < N_NODES) dinv[gid] = rsqrtf((float)v + 1.0f);
    tmp[t] = v;
    __syncthreads();
    for (int off = 1; off < 256; off <<= 1) {
        int add = (t >= off) ? tmp[t - off] : 0;
        __syncthreads();
        tmp[t] += add;
        __syncthreads();
    }
    part[gid] = tmp[t] - v;
    if (t == 255) bsum[blockIdx.x] = tmp[t];
}

__global__ __launch_bounds__(256) void k_scan2(int* __restrict__ bsum) {
    __shared__ int tmp[256];
    int t = threadIdx.x;
    int v = (t < 196) ? bsum[t] : 0;
    tmp[t] = v;
    __syncthreads();
    for (int off = 1; off < 256; off <<= 1) {
        int add = (t >= off) ? tmp[t - off] : 0;
        __syncthreads();
        tmp[t] += add;
        __syncthreads();
    }
    if (t < 196) bsum[t] = tmp[t] - v;
}

__global__ __launch_bounds__(256) void k_scan3(const int* __restrict__ part, const int* __restrict__ bsum,
                                               int* __restrict__ rowp) {
    int gid = blockIdx.x * 256 + threadIdx.x;
    rowp[gid] = part[gid] + bsum[blockIdx.x];
}

__global__ __launch_bounds__(256) void k_place(const int* __restrict__ src, const int* __restrict__ dst,
                                               const float* __restrict__ dinv, const int* __restrict__ rowp,
                                               int* __restrict__ cur, int* __restrict__ es, float* __restrict__ en) {
    int e = blockIdx.x * 256 + threadIdx.x;
    if (e >= N_EDGES) return;
    int s = src[e], d = dst[e];
    int p = atomicAdd(&cur[d], 1);
    int slot = rowp[d] + p;
    es[slot] = s;
    en[slot] = dinv[s] * dinv[d];
}

// ---------------- weight / bias pre-pack ----------------

__global__ __launch_bounds__(256) void k_wprep(const float* __restrict__ ew0, const float* __restrict__ ew,
                                               const float* __restrict__ ow0, const float* __restrict__ ow,
                                               const float* __restrict__ gw, unsigned* __restrict__ wpk) {
    int t = blockIdx.x * 256 + threadIdx.x;
    if (t >= 18 * 512) return;
    int lane = t & 63;
    int s = t >> 9;
    unsigned hu[8], lu[8];
    if (s < 14) {
        int q = (t >> 6) & 7;
        int mo = q >> 2, kts = q & 3;
        int fo = 32 * mo + (lane & 31);
#pragma unroll
        for (int i = 0; i < 8; ++i) {
            int fi = 16 * kts + 8 * (lane >> 5) + i;
            float w = 0.f;
            if (s == 0)       { if (fi < 16) w = ew0[fi * 64 + fo]; }
            else if (s <= 7)  w = ew[((s - 1) * 64 + fi) * 64 + fo];
            else if (s == 8)  w = ow0[(128 + fi) * 64 + fo];
            else if (s == 9)  w = ow0[fi * 64 + fo];
            else if (s == 10) w = ow0[(64 + fi) * 64 + fo];
            else              w = ow[((s - 11) * 64 + fi) * 64 + fo];
            unsigned u = __float_as_uint(w);
            unsigned h = u & 0xFFFF0000u;
            float d = w - __uint_as_float(h);
            hu[i] = h >> 16;
            lu[i] = __float_as_uint(d) >> 16;
        }
        uint4* o = (uint4*)wpk + (size_t)s * 1024 + (q * 2) * 64 + lane;
        o[0]  = make_uint4(hu[0] | (hu[1] << 16), hu[2] | (hu[3] << 16), hu[4] | (hu[5] << 16), hu[6] | (hu[7] << 16));
        o[64] = make_uint4(lu[0] | (lu[1] << 16), lu[2] | (lu[3] << 16), lu[4] | (lu[5] << 16), lu[6] | (lu[7] << 16));
    } else {
        int nt = (t >> 6) & 3;
        int kt = (t >> 8) & 1;
        int n = nt * 16 + (lane & 15);
#pragma unroll
        for (int i = 0; i < 8; ++i) {
            int k = kt * 32 + ((lane >> 4) * 8) + i;
            float w = gw[((s - 14) * 64 + k) * 64 + n];
            unsigned u = __float_as_uint(w);
            unsigned h = u & 0xFFFF0000u;
            float d = w - __uint_as_float(h);
            hu[i] = h >> 16;
            lu[i] = __float_as_uint(d) >> 16;
        }
        uint4* o = (uint4*)(wpk + (size_t)t * 8);
        o[0] = make_uint4(hu[0] | (hu[1] << 16), hu[2] | (hu[3] << 16), hu[4] | (hu[5] << 16), hu[6] | (hu[7] << 16));
        o[1] = make_uint4(lu[0] | (lu[1] << 16), lu[2] | (lu[3] << 16), lu[4] | (lu[5] << 16), lu[6] | (lu[7] << 16));
    }
}

__global__ __launch_bounds__(256) void k_bprep(const float* __restrict__ eb0, const float* __restrict__ eb,
                                               const float* __restrict__ ob0, const float* __restrict__ ob,
                                               const float* __restrict__ finw, const float* __restrict__ finb,
                                               float* __restrict__ bias3) {
    int t = blockIdx.x * 256 + threadIdx.x;
    if (t >= 1024) return;
    if (t == 15 * 64) { bias3[t] = finb[0]; return; }
    if (t > 15 * 64)  { bias3[t] = 0.f; return; }
    int s = t >> 6, idx = t & 63;
    int j = idx & 3, l5 = (idx >> 2) & 1, q = (idx >> 3) & 3, mo = idx >> 5;
    int f = 32 * mo + 8 * q + 4 * l5 + j;
    float b = 0.f;
    if (s == 0) b = eb0[f];
    else if (s <= 7) b = eb[(s - 1) * 64 + f];
    else if (s == 8) b = ob0[f];
    else if (s >= 11 && s <= 13) b = ob[(s - 11) * 64 + f];
    else if (s == 14) b = finw[f];
    bias3[t] = b;
}

// ---------------- shared split helpers ----------------

__device__ __forceinline__ void split_pack8(const float* xv, uint4& hfrag, uint4& lfrag) {
    unsigned hu[8], lu[8];
#pragma unroll
    for (int i = 0; i < 8; ++i) {
        unsigned u = __float_as_uint(xv[i]);
        unsigned h = u & 0xFFFF0000u;
        float d = xv[i] - __uint_as_float(h);
        hu[i] = h >> 16;
        lu[i] = __float_as_uint(d) >> 16;
    }
    hfrag = make_uint4(hu[0] | (hu[1] << 16), hu[2] | (hu[3] << 16), hu[4] | (hu[5] << 16), hu[6] | (hu[7] << 16));
    lfrag = make_uint4(lu[0] | (lu[1] << 16), lu[2] | (lu[3] << 16), lu[4] | (lu[5] << 16), lu[6] | (lu[7] << 16));
}

__device__ __forceinline__ void load_a_global_kt(const float* rowp, int kt, int g, uint4& aH, uint4& aL) {
    const float4* r4 = (const float4*)(rowp + kt * 32 + g * 8);
    float4 f0 = r4[0], f1 = r4[1];
    float xv[8] = {f0.x, f0.y, f0.z, f0.w, f1.x, f1.y, f1.z, f1.w};
    split_pack8(xv, aH, aL);
}

// 16x16x32 B-operand mfma (gcn node GEMM only)
__device__ __forceinline__ void mfma_stage(f32x4 acc[2][4], const uint4* wqs,
                                           const uint4 aH[2][2], const uint4 aL[2][2], int lane) {
#pragma unroll
    for (int kt = 0; kt < 2; ++kt) {
#pragma unroll
        for (int nt = 0; nt < 4; ++nt) {
            const uint4* wq = wqs + ((size_t)((kt * 4 + nt) * 64 + lane)) * 2;
            short8v bh = as_frag(wq[0]);
            short8v bl = as_frag(wq[1]);
#pragma unroll
            for (int mt = 0; mt < 2; ++mt) {
                short8v ah = as_frag(aH[mt][kt]);
                short8v al = as_frag(aL[mt][kt]);
                acc[mt][nt] = __builtin_amdgcn_mfma_f32_16x16x32_bf16(ah, bh, acc[mt][nt], 0, 0, 0);
                acc[mt][nt] = __builtin_amdgcn_mfma_f32_16x16x32_bf16(al, bh, acc[mt][nt], 0, 0, 0);
                acc[mt][nt] = __builtin_amdgcn_mfma_f32_16x16x32_bf16(ah, bl, acc[mt][nt], 0, 0, 0);
            }
        }
    }
}

// ---------------- GCN node GEMM: writes xl as f16 ----------------

__global__ __launch_bounds__(256, 3) void k_xlm(const float* __restrict__ xin,
                                                const unsigned* __restrict__ wpk, int stage,
                                                __half* __restrict__ xlh) {
    const int tid = threadIdx.x;
    const int wv = tid >> 6, lane = tid & 63;
    const int g = lane >> 4, l15 = lane & 15;
    const int rb = blockIdx.x * 128 + wv * 32;
    const uint4* wq = (const uint4*)wpk + (size_t)stage * 1024;

    f32x4 acc[2][4];
    uint4 aH[2][2], aL[2][2];
#pragma unroll
    for (int mt = 0; mt < 2; ++mt) {
        int row = rb + mt * 16 + l15;
        if (row < N_NODES) {
            const float* rowp = xin + (size_t)row * 64;
#pragma unroll
            for (int kt = 0; kt < 2; ++kt) load_a_global_kt(rowp, kt, g, aH[mt][kt], aL[mt][kt]);
        } else {
#pragma unroll
            for (int kt = 0; kt < 2; ++kt) { aH[mt][kt] = zero4(); aL[mt][kt] = zero4(); }
        }
#pragma unroll
        for (int nt = 0; nt < 4; ++nt) acc[mt][nt] = (f32x4){0.f, 0.f, 0.f, 0.f};
    }
    mfma_stage(acc, wq, aH, aL, lane);
#pragma unroll
    for (int mt = 0; mt < 2; ++mt)
#pragma unroll
        for (int nt = 0; nt < 4; ++nt)
#pragma unroll
            for (int r = 0; r < 4; ++r) {
                int row = rb + mt * 16 + g * 4 + r;
                if (row < N_NODES) xlh[(size_t)row * 64 + nt * 16 + l15] = __float2half(acc[mt][nt][r]);
            }
}

// ---------------- segmented aggregation: f16 gathers, shfl-broadcast es/en ----------------

__global__ __launch_bounds__(256) void k_agg(const __half* __restrict__ xlh,
                                             const int* __restrict__ es, const float* __restrict__ en,
                                             const int* __restrict__ rowp, const float* __restrict__ dinv,
                                             const float* __restrict__ b, float* __restrict__ xout,
                                             unsigned short* __restrict__ oh, unsigned short* __restrict__ ol,
                                             int writeSplit) {
    int n = blockIdx.x * 4 + (threadIdx.x >> 6);
    int j = threadIdx.x & 63;
    if (n >= N_NODES) return;
    const int i0 = rowp[n], e1 = rowp[n + 1];
    float a0 = 0.f, a1 = 0.f, a2 = 0.f, a3 = 0.f;
    for (int base = i0; base < e1; base += 64) {
        int cnt = e1 - base;
        if (cnt > 64) cnt = 64;
        int se = 0;
        float we = 0.f;
        if (base + j < e1) { se = es[base + j]; we = en[base + j]; }
        int k = 0;
        for (; k + 4 <= cnt; k += 4) {
            int s0 = __shfl(se, k + 0); float w0 = __shfl(we, k + 0);
            int s1 = __shfl(se, k + 1); float w1 = __shfl(we, k + 1);
            int s2 = __shfl(se, k + 2); float w2 = __shfl(we, k + 2);
            int s3 = __shfl(se, k + 3); float w3 = __shfl(we, k + 3);
            a0 = fmaf(w0, __half2float(xlh[(size_t)s0 * 64 + j]), a0);
            a1 = fmaf(w1, __half2float(xlh[(size_t)s1 * 64 + j]), a1);
            a2 = fmaf(w2, __half2float(xlh[(size_t)s2 * 64 + j]), a2);
            a3 = fmaf(w3, __half2float(xlh[(size_t)s3 * 64 + j]), a3);
        }
        for (; k < cnt; ++k) {
            int s0 = __shfl(se, k); float w0 = __shfl(we, k);
            a0 = fmaf(w0, __half2float(xlh[(size_t)s0 * 64 + j]), a0);
        }
    }
    float di = dinv[n];
    float val = (a0 + a1) + (a2 + a3) + di * di * __half2float(xlh[(size_t)n * 64 + j]) + b[j];
    float v = fmaxf(val, 0.f);
    size_t idx = (size_t)n * 64 + j;
    xout[idx] = v;
    if (writeSplit) {
        unsigned u = __float_as_uint(v);
        oh[idx] = (unsigned short)(u >> 16);
        float d = v - __uint_as_float(u & 0xFFFF0000u);
        ol[idx] = (unsigned short)(__float_as_uint(d) >> 16);
    }
}

// ---------------- fused edge mega kernel (R8 structure + setprio around MFMA) ----------------
// wave = 32 edges; acc = f32x16[2]; permlane32_swap inter-stage transpose;
// 16KB weight double-buffer via global_load_lds; 4 blocks/CU (proven sweet spot:
// R9 more-ILP -> spill cliff; R10 more-occupancy -> L2 thrash. Do not revisit.)

__device__ __forceinline__ void bias_init32(f32x16 acc[2], const float* bp) {
#pragma unroll
    for (int mo = 0; mo < 2; ++mo)
#pragma unroll
        for (int q = 0; q < 4; ++q) {
            float4 b = *(const float4*)(bp + (mo * 4 + q) * 8);
            acc[mo][4 * q + 0] = b.x;
            acc[mo][4 * q + 1] = b.y;
            acc[mo][4 * q + 2] = b.z;
            acc[mo][4 * q + 3] = b.w;
        }
}

// relu + split + native transpose via permlane32_swap.
__device__ __forceinline__ void exchange32(const f32x16 acc[2], unsigned BH[4][4], unsigned BL[4][4]) {
#pragma unroll
    for (int kts = 0; kts < 4; ++kts) {
        const int mo = kts >> 1;
        const int base = 8 * (kts & 1);
        float r0 = fmaxf(acc[mo][base + 0], 0.f), r1 = fmaxf(acc[mo][base + 1], 0.f);
        float r2 = fmaxf(acc[mo][base + 2], 0.f), r3 = fmaxf(acc[mo][base + 3], 0.f);
        float r4 = fmaxf(acc[mo][base + 4], 0.f), r5 = fmaxf(acc[mo][base + 5], 0.f);
        float r6 = fmaxf(acc[mo][base + 6], 0.f), r7 = fmaxf(acc[mo][base + 7], 0.f);
        unsigned pA0, pA1, pB0, pB1;
        asm("v_cvt_pk_bf16_f32 %0, %1, %2" : "=v"(pA0) : "v"(r0), "v"(r1));
        asm("v_cvt_pk_bf16_f32 %0, %1, %2" : "=v"(pA1) : "v"(r2), "v"(r3));
        asm("v_cvt_pk_bf16_f32 %0, %1, %2" : "=v"(pB0) : "v"(r4), "v"(r5));
        asm("v_cvt_pk_bf16_f32 %0, %1, %2" : "=v"(pB1) : "v"(r6), "v"(r7));
        float d0 = r0 - __uint_as_float(pA0 << 16);
        float d1 = r1 - __uint_as_float(pA0 & 0xFFFF0000u);
        float d2 = r2 - __uint_as_float(pA1 << 16);
        float d3 = r3 - __uint_as_float(pA1 & 0xFFFF0000u);
        float d4 = r4 - __uint_as_float(pB0 << 16);
        float d5 = r5 - __uint_as_float(pB0 & 0xFFFF0000u);
        float d6 = r6 - __uint_as_float(pB1 << 16);
        float d7 = r7 - __uint_as_float(pB1 & 0xFFFF0000u);
        unsigned qA0, qA1, qB0, qB1;
        asm("v_cvt_pk_bf16_f32 %0, %1, %2" : "=v"(qA0) : "v"(d0), "v"(d1));
        asm("v_cvt_pk_bf16_f32 %0, %1, %2" : "=v"(qA1) : "v"(d2), "v"(d3));
        asm("v_cvt_pk_bf16_f32 %0, %1, %2" : "=v"(qB0) : "v"(d4), "v"(d5));
        asm("v_cvt_pk_bf16_f32 %0, %1, %2" : "=v"(qB1) : "v"(d6), "v"(d7));
        uint2v sw0 = __builtin_amdgcn_permlane32_swap(pA0, pB0, false, false);
        uint2v sw1 = __builtin_amdgcn_permlane32_swap(pA1, pB1, false, false);
        BH[kts][0] = sw0[0]; BH[kts][1] = sw1[0]; BH[kts][2] = sw0[1]; BH[kts][3] = sw1[1];
        uint2v tw0 = __builtin_amdgcn_permlane32_swap(qA0, qB0, false, false);
        uint2v tw1 = __builtin_amdgcn_permlane32_swap(qA1, qB1, false, false);
        BL[kts][0] = tw0[0]; BL[kts][1] = tw1[0]; BL[kts][2] = tw0[1]; BL[kts][3] = tw1[1];
    }
}

__device__ __forceinline__ void loadB32(const unsigned short* xhi, const unsigned short* xlo,
                                        int node, int l5, unsigned BH[4][4], unsigned BL[4][4]) {
    const uint4* hp = (const uint4*)xhi + (size_t)node * 8;
    const uint4* lp = (const uint4*)xlo + (size_t)node * 8;
#pragma unroll
    for (int kts = 0; kts < 4; ++kts) {
        uint4 h = hp[2 * kts + l5];
        BH[kts][0] = h.x; BH[kts][1] = h.y; BH[kts][2] = h.z; BH[kts][3] = h.w;
        uint4 l = lp[2 * kts + l5];
        BL[kts][0] = l.x; BL[kts][1] = l.y; BL[kts][2] = l.z; BL[kts][3] = l.w;
    }
}

template <int KTS>
__device__ __forceinline__ void mfma32(f32x16 acc[2], const uint4* wl,
                                       const unsigned BH[4][4], const unsigned BL[4][4], int lane) {
    __builtin_amdgcn_s_setprio(1);
#pragma unroll
    for (int kt = 0; kt < KTS; ++kt) {
        short8v Bh = as_frag(make_uint4(BH[kt][0], BH[kt][1], BH[kt][2], BH[kt][3]));
        short8v Bl = as_frag(make_uint4(BL[kt][0], BL[kt][1], BL[kt][2], BL[kt][3]));
#pragma unroll
        for (int mo = 0; mo < 2; ++mo) {
            short8v Ah = as_frag(wl[((mo * 4 + kt) * 2 + 0) * 64 + lane]);
            short8v Al = as_frag(wl[((mo * 4 + kt) * 2 + 1) * 64 + lane]);
            acc[mo] = __builtin_amdgcn_mfma_f32_32x32x16_bf16(Ah, Bh, acc[mo], 0, 0, 0);
            acc[mo] = __builtin_amdgcn_mfma_f32_32x32x16_bf16(Al, Bh, acc[mo], 0, 0, 0);
            acc[mo] = __builtin_amdgcn_mfma_f32_32x32x16_bf16(Ah, Bl, acc[mo], 0, 0, 0);
        }
    }
    __builtin_amdgcn_s_setprio(0);
}

__global__ __launch_bounds__(256, 4) void k_mega(
    const float* __restrict__ ea, const int* __restrict__ src, const int* __restrict__ dst,
    const unsigned short* __restrict__ xhi, const unsigned short* __restrict__ xlo,
    const unsigned* __restrict__ wpk, const float* __restrict__ bias3,
    float* __restrict__ out) {
    __shared__ uint4 wlds[2][1024];   // 2 x 16 KB weight double-buffer
    __shared__ float blds[1024];      // bias / fin_w table
    const int tid = threadIdx.x;
    const int wv = tid >> 6, lane = tid & 63;
    const int l5 = lane >> 5, n = lane & 31;
    const int e = blockIdx.x * 128 + wv * 32 + n;
    const uint4* wpk4 = (const uint4*)wpk;

    // prologue: stage-0 weights (direct to LDS) + bias table
#pragma unroll
    for (int j = 0; j < 4; ++j) gload_lds16(wpk4 + tid + 256 * j, &wlds[0][tid + 256 * j]);
#pragma unroll
    for (int j = 0; j < 4; ++j) blds[tid + 256 * j] = bias3[tid + 256 * j];

    const int nsrc = src[e];
    const int ndst = dst[e];

    f32x16 acc[2];
    unsigned BH[4][4], BL[4][4];

    // s0 B-frags from edge_attr (K=16, slice 0 only)
    {
        const float4* ar = (const float4*)(ea + (size_t)e * 16 + 8 * l5);
        float4 f0 = ar[0], f1 = ar[1];
        float xv[8] = {f0.x, f0.y, f0.z, f0.w, f1.x, f1.y, f1.z, f1.w};
        uint4 hf, lf;
        split_pack8(xv, hf, lf);
        BH[0][0] = hf.x; BH[0][1] = hf.y; BH[0][2] = hf.z; BH[0][3] = hf.w;
        BL[0][0] = lf.x; BL[0][1] = lf.y; BL[0][2] = lf.z; BL[0][3] = lf.w;
    }
    __syncthreads();

    for (int s = 0; s < 14; ++s) {
        if (s < 13) {   // async direct-to-LDS prefetch of next-stage weights
            const uint4* np = wpk4 + (size_t)(s + 1) * 1024;
            uint4* nb = wlds[(s + 1) & 1];
#pragma unroll
            for (int j = 0; j < 4; ++j) gload_lds16(np + tid + 256 * j, &nb[tid + 256 * j]);
        }
        const uint4* wl = wlds[s & 1];
        if (s == 0) {
            bias_init32(acc, blds + l5 * 4);
            mfma32<1>(acc, wl, BH, BL, lane);
        } else if (s == 9 || s == 10) {
            loadB32(xhi, xlo, (s == 9) ? nsrc : ndst, l5, BH, BL);
            mfma32<4>(acc, wl, BH, BL, lane);     // accumulate into out-MLP acc
        } else {
            exchange32(acc, BH, BL);
            bias_init32(acc, blds + s * 64 + l5 * 4);
            mfma32<4>(acc, wl, BH, BL, lane);
        }
        __syncthreads();
    }

    // final dot: out = relu(P14)^T . fin_w + fin_b
    float v = 0.f;
#pragma unroll
    for (int mo = 0; mo < 2; ++mo)
#pragma unroll
        for (int q = 0; q < 4; ++q) {
            float4 w4 = *(const float4*)(blds + 14 * 64 + (mo * 4 + q) * 8 + l5 * 4);
            v = fmaf(fmaxf(acc[mo][4 * q + 0], 0.f), w4.x, v);
            v = fmaf(fmaxf(acc[mo][4 * q + 1], 0.f), w4.y, v);
            v = fmaf(fmaxf(acc[mo][4 * q + 2], 0.f), w4.z, v);
            v = fmaf(fmaxf(acc[mo][4 * q + 3], 0.f), w4.w, v);
        }
    v += __shfl_xor(v, 32, 64);
    if (lane < 32) out[e] = v + blds[15 * 64];
}

// ---------------- launch ----------------

extern "C" void kernel_launch(void* const* d_in, const int* in_sizes, int n_in,
                              void* d_out, int out_size, void* d_ws, size_t ws_size,
                              hipStream_t stream) {
    (void)in_sizes; (void)n_in; (void)out_size; (void)ws_size;

    const float* x         = (const float*)d_in[0];
    const int*   src       = (const int*)d_in[1];
    const int*   dst       = (const int*)d_in[2];
    const float* edge_attr = (const float*)d_in[3];
    const float* gcn_w     = (const float*)d_in[4];
    const float* gcn_b     = (const float*)d_in[5];
    const float* edge_w0   = (const float*)d_in[6];
    const float* edge_b0   = (const float*)d_in[7];
    const float* edge_w    = (const float*)d_in[8];
    const float* edge_b    = (const float*)d_in[9];
    const float* out_w0    = (const float*)d_in[10];
    const float* out_b0    = (const float*)d_in[11];
    const float* out_w     = (const float*)d_in[12];
    const float* out_b     = (const float*)d_in[13];
    const float* fin_w     = (const float*)d_in[14];
    const float* fin_b     = (const float*)d_in[15];
    float* out = (float*)d_out;

    float* ws    = (float*)d_ws;
    float* dinv  = ws;                                  // NPAD
    float* xbufA = dinv + NPAD;                         // N*64 f32
    __half* xlh  = (__half*)(xbufA + N_NODES * 64);     // N*64 f16
    unsigned short* xhi = (unsigned short*)((float*)xlh + N_NODES * 64);  // N*64 u16
    unsigned short* xlo = xhi + N_NODES * 64;                             // N*64 u16
    float* scr   = (float*)(xlo + N_NODES * 64);
    unsigned* wpk   = (unsigned*)scr;                   // 18*4096 = 73728 u32
    float* bias3    = scr + 73728;                      // 1024 padded
    int* degi       = (int*)(scr + 74816);              // NPAD
    int* cur        = degi + NPAD;                      // NPAD (adjacent for one memset)
    int* part       = cur + NPAD;                       // NPAD
    int* bsum       = part + NPAD;                      // 256
    int* rowp       = bsum + 256;                       // NPAD
    int* es         = rowp + NPAD;                      // E
    float* en       = (float*)(es + N_EDGES);           // E

    const int EB = N_EDGES / 256;                       // 3125
    const int NB = NPAD / 256;                          // 196

    hipMemsetAsync(degi, 0, 2 * NPAD * sizeof(int), stream);
    k_deg_i<<<EB, 256, 0, stream>>>(dst, degi);
    k_scan1<<<NB, 256, 0, stream>>>(degi, part, bsum, dinv);
    k_scan2<<<1, 256, 0, stream>>>(bsum);
    k_scan3<<<NB, 256, 0, stream>>>(part, bsum, rowp);
    k_place<<<EB, 256, 0, stream>>>(src, dst, dinv, rowp, cur, es, en);

    k_wprep<<<36, 256, 0, stream>>>(edge_w0, edge_w, out_w0, out_w, gcn_w, wpk);
    k_bprep<<<4, 256, 0, stream>>>(edge_b0, edge_b, out_b0, out_b, fin_w, fin_b, bias3);

    const float* xin = x;
    for (int layer = 0; layer < 4; ++layer) {
        k_xlm<<<(NPAD / 128), 256, 0, stream>>>(xin, wpk, 14 + layer, xlh);
        k_agg<<<(N_NODES + 3) / 4, 256, 0, stream>>>(xlh, es, en, rowp, dinv,
                                                     gcn_b + layer * 64, xbufA,
                                                     xhi, xlo, (layer == 3) ? 1 : 0);
        xin = xbufA;
    }

    k_mega<<<N_EDGES / 128, 256, 0, stream>>>(edge_attr, src, dst, xhi, xlo,
                                              wpk, bias3, out);
}

// Round 12
// 488.988 us; speedup vs baseline: 3.9340x; 1.0239x over previous
//
#include <hip/hip_runtime.h>
#include <hip/hip_fp16.h>

#define N_NODES 50000
#define N_EDGES 800000
#define NPAD 50176   // 196*256

typedef __attribute__((ext_vector_type(8))) short short8v;   // 8 bf16 (4 VGPR)
typedef __attribute__((ext_vector_type(4))) float f32x4;
typedef __attribute__((ext_vector_type(16))) float f32x16;
typedef __attribute__((ext_vector_type(2))) unsigned uint2v;

union U4S8 { uint4 u; short8v s; };
__device__ __forceinline__ short8v as_frag(uint4 u) { U4S8 t; t.u = u; return t.s; }
__device__ __forceinline__ uint4 zero4() { return make_uint4(0u, 0u, 0u, 0u); }

// direct global->LDS 16B copy (linear both sides)
__device__ __forceinline__ void gload_lds16(const uint4* g, uint4* l) {
    __builtin_amdgcn_global_load_lds((const __attribute__((address_space(1))) void*)g,
                                     (__attribute__((address_space(3))) void*)l, 16, 0, 0);
}

// ---------------- degree / CSR build ----------------

__global__ __launch_bounds__(256) void k_deg_i(const int* __restrict__ dst, int* __restrict__ degi) {
    int e = blockIdx.x * 256 + threadIdx.x;
    if (e < N_EDGES) atomicAdd(&degi[dst[e]], 1);
}

__global__ __launch_bounds__(256) void k_scan1(const int* __restrict__ degi, int* __restrict__ part,
                                               int* __restrict__ bsum, float* __restrict__ dinv) {
    __shared__ int tmp[256];
    int t = threadIdx.x, gid = blockIdx.x * 256 + t;
    int v = degi[gid];
    if (gid < N_NODES) dinv[gid] = rsqrtf((float)v + 1.0f);
    tmp[t] = v;
    __syncthreads();
    for (int off = 1; off < 256; off <<= 1) {
        int add = (t >= off) ? tmp[t - off] : 0;
        __syncthreads();
        tmp[t] += add;
        __syncthreads();
    }
    part[gid] = tmp[t] - v;
    if (t == 255) bsum[blockIdx.x] = tmp[t];
}

__global__ __launch_bounds__(256) void k_scan2(int* __restrict__ bsum) {
    __shared__ int tmp[256];
    int t = threadIdx.x;
    int v = (t < 196) ? bsum[t] : 0;
    tmp[t] = v;
    __syncthreads();
    for (int off = 1; off < 256; off <<= 1) {
        int add = (t >= off) ? tmp[t - off] : 0;
        __syncthreads();
        tmp[t] += add;
        __syncthreads();
    }
    if (t < 196) bsum[t] = tmp[t] - v;
}

__global__ __launch_bounds__(256) void k_scan3(const int* __restrict__ part, const int* __restrict__ bsum,
                                               int* __restrict__ rowp) {
    int gid = blockIdx.x * 256 + threadIdx.x;
    rowp[gid] = part[gid] + bsum[blockIdx.x];
}

__global__ __launch_bounds__(256) void k_place(const int* __restrict__ src, const int* __restrict__ dst,
                                               const float* __restrict__ dinv, const int* __restrict__ rowp,
                                               int* __restrict__ cur, int* __restrict__ es, float* __restrict__ en) {
    int e = blockIdx.x * 256 + threadIdx.x;
    if (e >= N_EDGES) return;
    int s = src[e], d = dst[e];
    int p = atomicAdd(&cur[d], 1);
    int slot = rowp[d] + p;
    es[slot] = s;
    en[slot] = dinv[s] * dinv[d];
}

// ---------------- weight / bias pre-pack ----------------

__global__ __launch_bounds__(256) void k_wprep(const float* __restrict__ ew0, const float* __restrict__ ew,
                                               const float* __restrict__ ow0, const float* __restrict__ ow,
                                               const float* __restrict__ gw, unsigned* __restrict__ wpk) {
    int t = blockIdx.x * 256 + threadIdx.x;
    if (t >= 18 * 512) return;
    int lane = t & 63;
    int s = t >> 9;
    unsigned hu[8], lu[8];
    if (s < 14) {
        int q = (t >> 6) & 7;
        int mo = q >> 2, kts = q & 3;
        int fo = 32 * mo + (lane & 31);
#pragma unroll
        for (int i = 0; i < 8; ++i) {
            int fi = 16 * kts + 8 * (lane >> 5) + i;
            float w = 0.f;
            if (s == 0)       { if (fi < 16) w = ew0[fi * 64 + fo]; }
            else if (s <= 7)  w = ew[((s - 1) * 64 + fi) * 64 + fo];
            else if (s == 8)  w = ow0[(128 + fi) * 64 + fo];
            else if (s == 9)  w = ow0[fi * 64 + fo];
            else if (s == 10) w = ow0[(64 + fi) * 64 + fo];
            else              w = ow[((s - 11) * 64 + fi) * 64 + fo];
            unsigned u = __float_as_uint(w);
            unsigned h = u & 0xFFFF0000u;
            float d = w - __uint_as_float(h);
            hu[i] = h >> 16;
            lu[i] = __float_as_uint(d) >> 16;
        }
        uint4* o = (uint4*)wpk + (size_t)s * 1024 + (q * 2) * 64 + lane;
        o[0]  = make_uint4(hu[0] | (hu[1] << 16), hu[2] | (hu[3] << 16), hu[4] | (hu[5] << 16), hu[6] | (hu[7] << 16));
        o[64] = make_uint4(lu[0] | (lu[1] << 16), lu[2] | (lu[3] << 16), lu[4] | (lu[5] << 16), lu[6] | (lu[7] << 16));
    } else {
        int nt = (t >> 6) & 3;
        int kt = (t >> 8) & 1;
        int n = nt * 16 + (lane & 15);
#pragma unroll
        for (int i = 0; i < 8; ++i) {
            int k = kt * 32 + ((lane >> 4) * 8) + i;
            float w = gw[((s - 14) * 64 + k) * 64 + n];
            unsigned u = __float_as_uint(w);
            unsigned h = u & 0xFFFF0000u;
            float d = w - __uint_as_float(h);
            hu[i] = h >> 16;
            lu[i] = __float_as_uint(d) >> 16;
        }
        uint4* o = (uint4*)(wpk + (size_t)t * 8);
        o[0] = make_uint4(hu[0] | (hu[1] << 16), hu[2] | (hu[3] << 16), hu[4] | (hu[5] << 16), hu[6] | (hu[7] << 16));
        o[1] = make_uint4(lu[0] | (lu[1] << 16), lu[2] | (lu[3] << 16), lu[4] | (lu[5] << 16), lu[6] | (lu[7] << 16));
    }
}

__global__ __launch_bounds__(256) void k_bprep(const float* __restrict__ eb0, const float* __restrict__ eb,
                                               const float* __restrict__ ob0, const float* __restrict__ ob,
                                               const float* __restrict__ finw, const float* __restrict__ finb,
                                               float* __restrict__ bias3) {
    int t = blockIdx.x * 256 + threadIdx.x;
    if (t >= 1024) return;
    if (t == 15 * 64) { bias3[t] = finb[0]; return; }
    if (t > 15 * 64)  { bias3[t] = 0.f; return; }
    int s = t >> 6, idx = t & 63;
    int j = idx & 3, l5 = (idx >> 2) & 1, q = (idx >> 3) & 3, mo = idx >> 5;
    int f = 32 * mo + 8 * q + 4 * l5 + j;
    float b = 0.f;
    if (s == 0) b = eb0[f];
    else if (s <= 7) b = eb[(s - 1) * 64 + f];
    else if (s == 8) b = ob0[f];
    else if (s >= 11 && s <= 13) b = ob[(s - 11) * 64 + f];
    else if (s == 14) b = finw[f];
    bias3[t] = b;
}

// ---------------- shared split helpers ----------------

__device__ __forceinline__ void split_pack8(const float* xv, uint4& hfrag, uint4& lfrag) {
    unsigned hu[8], lu[8];
#pragma unroll
    for (int i = 0; i < 8; ++i) {
        unsigned u = __float_as_uint(xv[i]);
        unsigned h = u & 0xFFFF0000u;
        float d = xv[i] - __uint_as_float(h);
        hu[i] = h >> 16;
        lu[i] = __float_as_uint(d) >> 16;
    }
    hfrag = make_uint4(hu[0] | (hu[1] << 16), hu[2] | (hu[3] << 16), hu[4] | (hu[5] << 16), hu[6] | (hu[7] << 16));
    lfrag = make_uint4(lu[0] | (lu[1] << 16), lu[2] | (lu[3] << 16), lu[4] | (lu[5] << 16), lu[6] | (lu[7] << 16));
}

__device__ __forceinline__ void load_a_global_kt(const float* rowp, int kt, int g, uint4& aH, uint4& aL) {
    const float4* r4 = (const float4*)(rowp + kt * 32 + g * 8);
    float4 f0 = r4[0], f1 = r4[1];
    float xv[8] = {f0.x, f0.y, f0.z, f0.w, f1.x, f1.y, f1.z, f1.w};
    split_pack8(xv, aH, aL);
}

// 16x16x32 B-operand mfma (gcn node GEMM only)
__device__ __forceinline__ void mfma_stage(f32x4 acc[2][4], const uint4* wqs,
                                           const uint4 aH[2][2], const uint4 aL[2][2], int lane) {
#pragma unroll
    for (int kt = 0; kt < 2; ++kt) {
#pragma unroll
        for (int nt = 0; nt < 4; ++nt) {
            const uint4* wq = wqs + ((size_t)((kt * 4 + nt) * 64 + lane)) * 2;
            short8v bh = as_frag(wq[0]);
            short8v bl = as_frag(wq[1]);
#pragma unroll
            for (int mt = 0; mt < 2; ++mt) {
                short8v ah = as_frag(aH[mt][kt]);
                short8v al = as_frag(aL[mt][kt]);
                acc[mt][nt] = __builtin_amdgcn_mfma_f32_16x16x32_bf16(ah, bh, acc[mt][nt], 0, 0, 0);
                acc[mt][nt] = __builtin_amdgcn_mfma_f32_16x16x32_bf16(al, bh, acc[mt][nt], 0, 0, 0);
                acc[mt][nt] = __builtin_amdgcn_mfma_f32_16x16x32_bf16(ah, bl, acc[mt][nt], 0, 0, 0);
            }
        }
    }
}

// ---------------- GCN node GEMM: writes xl as f16 ----------------

__global__ __launch_bounds__(256, 3) void k_xlm(const float* __restrict__ xin,
                                                const unsigned* __restrict__ wpk, int stage,
                                                __half* __restrict__ xlh) {
    const int tid = threadIdx.x;
    const int wv = tid >> 6, lane = tid & 63;
    const int g = lane >> 4, l15 = lane & 15;
    const int rb = blockIdx.x * 128 + wv * 32;
    const uint4* wq = (const uint4*)wpk + (size_t)stage * 1024;

    f32x4 acc[2][4];
    uint4 aH[2][2], aL[2][2];
#pragma unroll
    for (int mt = 0; mt < 2; ++mt) {
        int row = rb + mt * 16 + l15;
        if (row < N_NODES) {
            const float* rowp = xin + (size_t)row * 64;
#pragma unroll
            for (int kt = 0; kt < 2; ++kt) load_a_global_kt(rowp, kt, g, aH[mt][kt], aL[mt][kt]);
        } else {
#pragma unroll
            for (int kt = 0; kt < 2; ++kt) { aH[mt][kt] = zero4(); aL[mt][kt] = zero4(); }
        }
#pragma unroll
        for (int nt = 0; nt < 4; ++nt) acc[mt][nt] = (f32x4){0.f, 0.f, 0.f, 0.f};
    }
    mfma_stage(acc, wq, aH, aL, lane);
#pragma unroll
    for (int mt = 0; mt < 2; ++mt)
#pragma unroll
        for (int nt = 0; nt < 4; ++nt)
#pragma unroll
            for (int r = 0; r < 4; ++r) {
                int row = rb + mt * 16 + g * 4 + r;
                if (row < N_NODES) xlh[(size_t)row * 64 + nt * 16 + l15] = __float2half(acc[mt][nt][r]);
            }
}

// ---------------- segmented aggregation: f16 gathers, shfl-broadcast es/en ----------------

__global__ __launch_bounds__(256) void k_agg(const __half* __restrict__ xlh,
                                             const int* __restrict__ es, const float* __restrict__ en,
                                             const int* __restrict__ rowp, const float* __restrict__ dinv,
                                             const float* __restrict__ b, float* __restrict__ xout,
                                             unsigned short* __restrict__ oh, unsigned short* __restrict__ ol,
                                             int writeSplit) {
    int n = blockIdx.x * 4 + (threadIdx.x >> 6);
    int j = threadIdx.x & 63;
    if (n >= N_NODES) return;
    const int i0 = rowp[n], e1 = rowp[n + 1];
    float a0 = 0.f, a1 = 0.f, a2 = 0.f, a3 = 0.f;
    for (int base = i0; base < e1; base += 64) {
        int cnt = e1 - base;
        if (cnt > 64) cnt = 64;
        int se = 0;
        float we = 0.f;
        if (base + j < e1) { se = es[base + j]; we = en[base + j]; }
        int k = 0;
        for (; k + 4 <= cnt; k += 4) {
            int s0 = __shfl(se, k + 0); float w0 = __shfl(we, k + 0);
            int s1 = __shfl(se, k + 1); float w1 = __shfl(we, k + 1);
            int s2 = __shfl(se, k + 2); float w2 = __shfl(we, k + 2);
            int s3 = __shfl(se, k + 3); float w3 = __shfl(we, k + 3);
            a0 = fmaf(w0, __half2float(xlh[(size_t)s0 * 64 + j]), a0);
            a1 = fmaf(w1, __half2float(xlh[(size_t)s1 * 64 + j]), a1);
            a2 = fmaf(w2, __half2float(xlh[(size_t)s2 * 64 + j]), a2);
            a3 = fmaf(w3, __half2float(xlh[(size_t)s3 * 64 + j]), a3);
        }
        for (; k < cnt; ++k) {
            int s0 = __shfl(se, k); float w0 = __shfl(we, k);
            a0 = fmaf(w0, __half2float(xlh[(size_t)s0 * 64 + j]), a0);
        }
    }
    float di = dinv[n];
    float val = (a0 + a1) + (a2 + a3) + di * di * __half2float(xlh[(size_t)n * 64 + j]) + b[j];
    float v = fmaxf(val, 0.f);
    size_t idx = (size_t)n * 64 + j;
    xout[idx] = v;
    if (writeSplit) {
        unsigned u = __float_as_uint(v);
        oh[idx] = (unsigned short)(u >> 16);
        float d = v - __uint_as_float(u & 0xFFFF0000u);
        ol[idx] = (unsigned short)(__float_as_uint(d) >> 16);
    }
}

// ---------------- fused edge mega kernel (R8 structure — proven local optimum) ----------------
// wave = 32 edges; acc = f32x16[2]; permlane32_swap inter-stage transpose;
// 16KB weight double-buffer via global_load_lds; 4 blocks/CU.
// Measured dead ends around this point: R9 2-tiles/wave -> VGPR spill cliff (4x);
// R10 8KB half-stages 6 blocks/CU -> L2 thrash (4x); R11 setprio -> -10%.

__device__ __forceinline__ void bias_init32(f32x16 acc[2], const float* bp) {
#pragma unroll
    for (int mo = 0; mo < 2; ++mo)
#pragma unroll
        for (int q = 0; q < 4; ++q) {
            float4 b = *(const float4*)(bp + (mo * 4 + q) * 8);
            acc[mo][4 * q + 0] = b.x;
            acc[mo][4 * q + 1] = b.y;
            acc[mo][4 * q + 2] = b.z;
            acc[mo][4 * q + 3] = b.w;
        }
}

// relu + split + native transpose via permlane32_swap.
__device__ __forceinline__ void exchange32(const f32x16 acc[2], unsigned BH[4][4], unsigned BL[4][4]) {
#pragma unroll
    for (int kts = 0; kts < 4; ++kts) {
        const int mo = kts >> 1;
        const int base = 8 * (kts & 1);
        float r0 = fmaxf(acc[mo][base + 0], 0.f), r1 = fmaxf(acc[mo][base + 1], 0.f);
        float r2 = fmaxf(acc[mo][base + 2], 0.f), r3 = fmaxf(acc[mo][base + 3], 0.f);
        float r4 = fmaxf(acc[mo][base + 4], 0.f), r5 = fmaxf(acc[mo][base + 5], 0.f);
        float r6 = fmaxf(acc[mo][base + 6], 0.f), r7 = fmaxf(acc[mo][base + 7], 0.f);
        unsigned pA0, pA1, pB0, pB1;
        asm("v_cvt_pk_bf16_f32 %0, %1, %2" : "=v"(pA0) : "v"(r0), "v"(r1));
        asm("v_cvt_pk_bf16_f32 %0, %1, %2" : "=v"(pA1) : "v"(r2), "v"(r3));
        asm("v_cvt_pk_bf16_f32 %0, %1, %2" : "=v"(pB0) : "v"(r4), "v"(r5));
        asm("v_cvt_pk_bf16_f32 %0, %1, %2" : "=v"(pB1) : "v"(r6), "v"(r7));
        float d0 = r0 - __uint_as_float(pA0 << 16);
        float d1 = r1 - __uint_as_float(pA0 & 0xFFFF0000u);
        float d2 = r2 - __uint_as_float(pA1 << 16);
        float d3 = r3 - __uint_as_float(pA1 & 0xFFFF0000u);
        float d4 = r4 - __uint_as_float(pB0 << 16);
        float d5 = r5 - __uint_as_float(pB0 & 0xFFFF0000u);
        float d6 = r6 - __uint_as_float(pB1 << 16);
        float d7 = r7 - __uint_as_float(pB1 & 0xFFFF0000u);
        unsigned qA0, qA1, qB0, qB1;
        asm("v_cvt_pk_bf16_f32 %0, %1, %2" : "=v"(qA0) : "v"(d0), "v"(d1));
        asm("v_cvt_pk_bf16_f32 %0, %1, %2" : "=v"(qA1) : "v"(d2), "v"(d3));
        asm("v_cvt_pk_bf16_f32 %0, %1, %2" : "=v"(qB0) : "v"(d4), "v"(d5));
        asm("v_cvt_pk_bf16_f32 %0, %1, %2" : "=v"(qB1) : "v"(d6), "v"(d7));
        uint2v sw0 = __builtin_amdgcn_permlane32_swap(pA0, pB0, false, false);
        uint2v sw1 = __builtin_amdgcn_permlane32_swap(pA1, pB1, false, false);
        BH[kts][0] = sw0[0]; BH[kts][1] = sw1[0]; BH[kts][2] = sw0[1]; BH[kts][3] = sw1[1];
        uint2v tw0 = __builtin_amdgcn_permlane32_swap(qA0, qB0, false, false);
        uint2v tw1 = __builtin_amdgcn_permlane32_swap(qA1, qB1, false, false);
        BL[kts][0] = tw0[0]; BL[kts][1] = tw1[0]; BL[kts][2] = tw0[1]; BL[kts][3] = tw1[1];
    }
}

__device__ __forceinline__ void loadB32(const unsigned short* xhi, const unsigned short* xlo,
                                        int node, int l5, unsigned BH[4][4], unsigned BL[4][4]) {
    const uint4* hp = (const uint4*)xhi + (size_t)node * 8;
    const uint4* lp = (const uint4*)xlo + (size_t)node * 8;
#pragma unroll
    for (int kts = 0; kts < 4; ++kts) {
        uint4 h = hp[2 * kts + l5];
        BH[kts][0] = h.x; BH[kts][1] = h.y; BH[kts][2] = h.z; BH[kts][3] = h.w;
        uint4 l = lp[2 * kts + l5];
        BL[kts][0] = l.x; BL[kts][1] = l.y; BL[kts][2] = l.z; BL[kts][3] = l.w;
    }
}

template <int KTS>
__device__ __forceinline__ void mfma32(f32x16 acc[2], const uint4* wl,
                                       const unsigned BH[4][4], const unsigned BL[4][4], int lane) {
#pragma unroll
    for (int kt = 0; kt < KTS; ++kt) {
        short8v Bh = as_frag(make_uint4(BH[kt][0], BH[kt][1], BH[kt][2], BH[kt][3]));
        short8v Bl = as_frag(make_uint4(BL[kt][0], BL[kt][1], BL[kt][2], BL[kt][3]));
#pragma unroll
        for (int mo = 0; mo < 2; ++mo) {
            short8v Ah = as_frag(wl[((mo * 4 + kt) * 2 + 0) * 64 + lane]);
            short8v Al = as_frag(wl[((mo * 4 + kt) * 2 + 1) * 64 + lane]);
            acc[mo] = __builtin_amdgcn_mfma_f32_32x32x16_bf16(Ah, Bh, acc[mo], 0, 0, 0);
            acc[mo] = __builtin_amdgcn_mfma_f32_32x32x16_bf16(Al, Bh, acc[mo], 0, 0, 0);
            acc[mo] = __builtin_amdgcn_mfma_f32_32x32x16_bf16(Ah, Bl, acc[mo], 0, 0, 0);
        }
    }
}

__global__ __launch_bounds__(256, 4) void k_mega(
    const float* __restrict__ ea, const int* __restrict__ src, const int* __restrict__ dst,
    const unsigned short* __restrict__ xhi, const unsigned short* __restrict__ xlo,
    const unsigned* __restrict__ wpk, const float* __restrict__ bias3,
    float* __restrict__ out) {
    __shared__ uint4 wlds[2][1024];   // 2 x 16 KB weight double-buffer
    __shared__ float blds[1024];      // bias / fin_w table
    const int tid = threadIdx.x;
    const int wv = tid >> 6, lane = tid & 63;
    const int l5 = lane >> 5, n = lane & 31;
    const int e = blockIdx.x * 128 + wv * 32 + n;
    const uint4* wpk4 = (const uint4*)wpk;

    // prologue: stage-0 weights (direct to LDS) + bias table
#pragma unroll
    for (int j = 0; j < 4; ++j) gload_lds16(wpk4 + tid + 256 * j, &wlds[0][tid + 256 * j]);
#pragma unroll
    for (int j = 0; j < 4; ++j) blds[tid + 256 * j] = bias3[tid + 256 * j];

    const int nsrc = src[e];
    const int ndst = dst[e];

    f32x16 acc[2];
    unsigned BH[4][4], BL[4][4];

    // s0 B-frags from edge_attr (K=16, slice 0 only)
    {
        const float4* ar = (const float4*)(ea + (size_t)e * 16 + 8 * l5);
        float4 f0 = ar[0], f1 = ar[1];
        float xv[8] = {f0.x, f0.y, f0.z, f0.w, f1.x, f1.y, f1.z, f1.w};
        uint4 hf, lf;
        split_pack8(xv, hf, lf);
        BH[0][0] = hf.x; BH[0][1] = hf.y; BH[0][2] = hf.z; BH[0][3] = hf.w;
        BL[0][0] = lf.x; BL[0][1] = lf.y; BL[0][2] = lf.z; BL[0][3] = lf.w;
    }
    __syncthreads();

    for (int s = 0; s < 14; ++s) {
        if (s < 13) {   // async direct-to-LDS prefetch of next-stage weights
            const uint4* np = wpk4 + (size_t)(s + 1) * 1024;
            uint4* nb = wlds[(s + 1) & 1];
#pragma unroll
            for (int j = 0; j < 4; ++j) gload_lds16(np + tid + 256 * j, &nb[tid + 256 * j]);
        }
        const uint4* wl = wlds[s & 1];
        if (s == 0) {
            bias_init32(acc, blds + l5 * 4);
            mfma32<1>(acc, wl, BH, BL, lane);
        } else if (s == 9 || s == 10) {
            loadB32(xhi, xlo, (s == 9) ? nsrc : ndst, l5, BH, BL);
            mfma32<4>(acc, wl, BH, BL, lane);     // accumulate into out-MLP acc
        } else {
            exchange32(acc, BH, BL);
            bias_init32(acc, blds + s * 64 + l5 * 4);
            mfma32<4>(acc, wl, BH, BL, lane);
        }
        __syncthreads();
    }

    // final dot: out = relu(P14)^T . fin_w + fin_b
    float v = 0.f;
#pragma unroll
    for (int mo = 0; mo < 2; ++mo)
#pragma unroll
        for (int q = 0; q < 4; ++q) {
            float4 w4 = *(const float4*)(blds + 14 * 64 + (mo * 4 + q) * 8 + l5 * 4);
            v = fmaf(fmaxf(acc[mo][4 * q + 0], 0.f), w4.x, v);
            v = fmaf(fmaxf(acc[mo][4 * q + 1], 0.f), w4.y, v);
            v = fmaf(fmaxf(acc[mo][4 * q + 2], 0.f), w4.z, v);
            v = fmaf(fmaxf(acc[mo][4 * q + 3], 0.f), w4.w, v);
        }
    v += __shfl_xor(v, 32, 64);
    if (lane < 32) out[e] = v + blds[15 * 64];
}

// ---------------- launch ----------------

extern "C" void kernel_launch(void* const* d_in, const int* in_sizes, int n_in,
                              void* d_out, int out_size, void* d_ws, size_t ws_size,
                              hipStream_t stream) {
    (void)in_sizes; (void)n_in; (void)out_size; (void)ws_size;

    const float* x         = (const float*)d_in[0];
    const int*   src       = (const int*)d_in[1];
    const int*   dst       = (const int*)d_in[2];
    const float* edge_attr = (const float*)d_in[3];
    const float* gcn_w     = (const float*)d_in[4];
    const float* gcn_b     = (const float*)d_in[5];
    const float* edge_w0   = (const float*)d_in[6];
    const float* edge_b0   = (const float*)d_in[7];
    const float* edge_w    = (const float*)d_in[8];
    const float* edge_b    = (const float*)d_in[9];
    const float* out_w0    = (const float*)d_in[10];
    const float* out_b0    = (const float*)d_in[11];
    const float* out_w     = (const float*)d_in[12];
    const float* out_b     = (const float*)d_in[13];
    const float* fin_w     = (const float*)d_in[14];
    const float* fin_b     = (const float*)d_in[15];
    float* out = (float*)d_out;

    float* ws    = (float*)d_ws;
    float* dinv  = ws;                                  // NPAD
    float* xbufA = dinv + NPAD;                         // N*64 f32
    __half* xlh  = (__half*)(xbufA + N_NODES * 64);     // N*64 f16
    unsigned short* xhi = (unsigned short*)((float*)xlh + N_NODES * 64);  // N*64 u16
    unsigned short* xlo = xhi + N_NODES * 64;                             // N*64 u16
    float* scr   = (float*)(xlo + N_NODES * 64);
    unsigned* wpk   = (unsigned*)scr;                   // 18*4096 = 73728 u32
    float* bias3    = scr + 73728;                      // 1024 padded
    int* degi       = (int*)(scr + 74816);              // NPAD
    int* cur        = degi + NPAD;                      // NPAD (adjacent for one memset)
    int* part       = cur + NPAD;                       // NPAD
    int* bsum       = part + NPAD;                      // 256
    int* rowp       = bsum + 256;                       // NPAD
    int* es         = rowp + NPAD;                      // E
    float* en       = (float*)(es + N_EDGES);           // E

    const int EB = N_EDGES / 256;                       // 3125
    const int NB = NPAD / 256;                          // 196

    hipMemsetAsync(degi, 0, 2 * NPAD * sizeof(int), stream);
    k_deg_i<<<EB, 256, 0, stream>>>(dst, degi);
    k_scan1<<<NB, 256, 0, stream>>>(degi, part, bsum, dinv);
    k_scan2<<<1, 256, 0, stream>>>(bsum);
    k_scan3<<<NB, 256, 0, stream>>>(part, bsum, rowp);
    k_place<<<EB, 256, 0, stream>>>(src, dst, dinv, rowp, cur, es, en);

    k_wprep<<<36, 256, 0, stream>>>(edge_w0, edge_w, out_w0, out_w, gcn_w, wpk);
    k_bprep<<<4, 256, 0, stream>>>(edge_b0, edge_b, out_b0, out_b, fin_w, fin_b, bias3);

    const float* xin = x;
    for (int layer = 0; layer < 4; ++layer) {
        k_xlm<<<(NPAD / 128), 256, 0, stream>>>(xin, wpk, 14 + layer, xlh);
        k_agg<<<(N_NODES + 3) / 4, 256, 0, stream>>>(xlh, es, en, rowp, dinv,
                                                     gcn_b + layer * 64, xbufA,
                                                     xhi, xlo, (layer == 3) ? 1 : 0);
        xin = xbufA;
    }

    k_mega<<<N_EDGES / 128, 256, 0, stream>>>(edge_attr, src, dst, xhi, xlo,
                                              wpk, bias3, out);
}